// Round 1
// baseline (1428.605 us; speedup 1.0000x reference)
//
#include <hip/hip_runtime.h>
#include <math.h>

#define EC 8           // edges per chunk in aggregate kernel
#define FDIM 64

// CG tensor offsets inside cg buffer (floats)
#define CG110 0
#define CG220 9
#define CG121 34
#define CG211 79
#define CG231 124
#define CG112 229
#define CG132 274
#define CG222 379
#define CGTOT 504

// ---------------- CG coefficient init (device, double precision) ----------------
__device__ double dfact(int n){ double r=1.0; for(int i=2;i<=n;i++) r*=(double)i; return r; }

__device__ double cg_coeff(int j1,int m1,int j2,int m2,int j3,int m3){
  if(m1+m2!=m3) return 0.0;
  int lo = j1>j2 ? j1-j2 : j2-j1;
  if(j3 < lo || j3 > j1+j2) return 0.0;
  double pref = sqrt((double)(2*j3+1)*dfact(j3+j1-j2)*dfact(j3-j1+j2)*dfact(j1+j2-j3)/dfact(j1+j2+j3+1));
  pref *= sqrt(dfact(j3+m3)*dfact(j3-m3)*dfact(j1-m1)*dfact(j1+m1)*dfact(j2-m2)*dfact(j2+m2));
  double s=0.0;
  for(int k=0;k<=j1+j2+j3;k++){
    int d0=j1+j2-j3-k, d1=j1-m1-k, d2=j2+m2-k, d3=j3-j2+m1+k, d4=j3-j1-m2+k;
    if(d0<0||d1<0||d2<0||d3<0||d4<0) continue;
    double term = 1.0/(dfact(k)*dfact(d0)*dfact(d1)*dfact(d2)*dfact(d3)*dfact(d4));
    s += (k&1)? -term : term;
  }
  return pref*s;
}

// U[i][a] for real-spherical-harmonic change of basis, complex value (re,im)
__device__ void u_elem(int l,int i,int a,double& re,double& im){
  const double s=0.70710678118654752440;
  re=0.0; im=0.0;
  int mi=i-l, ma=a-l;
  if(mi==0){ if(ma==0) re=1.0; }
  else if(mi>0){ if(ma==mi) re=(mi&1)?-s:s; else if(ma==-mi) re=s; }
  else { int m=-mi; if(ma==mi) im=s; else if(ma==-mi) im=(m&1)?s:-s; }
}

__device__ float real_cg_elem(int l1,int l2,int l3,int ii,int jj,int kk){
  double acc=0.0;
  int alist[2]={ii, 2*l1-ii}; int na=(alist[1]==alist[0])?1:2;
  int blist[2]={jj, 2*l2-jj}; int nb=(blist[1]==blist[0])?1:2;
  int clist[2]={kk, 2*l3-kk}; int nc=(clist[1]==clist[0])?1:2;
  for(int ai=0;ai<na;ai++) for(int bi=0;bi<nb;bi++) for(int ci=0;ci<nc;ci++){
    int a=alist[ai], b=blist[bi], c=clist[ci];
    double w = cg_coeff(l1,a-l1,l2,b-l2,l3,c-l3);
    if(w==0.0) continue;
    double u1r,u1i,u2r,u2i,u3r,u3i;
    u_elem(l1,ii,a,u1r,u1i); u_elem(l2,jj,b,u2r,u2i); u_elem(l3,kk,c,u3r,u3i);
    double ar = u1r*u2r - u1i*u2i;
    double aiv= u1r*u2i + u1i*u2r;
    acc += (ar*u3r + aiv*u3i)*w;   // times conj(U3), real part; Cc is real
  }
  return (float)acc;
}

__global__ void cg_init_kernel(float* __restrict__ cgbuf){
  int tid = blockIdx.x*blockDim.x + threadIdx.x;
  if(tid>=CGTOT) return;
  const int l1s[8]={1,2,1,2,2,1,1,2};
  const int l2s[8]={1,2,2,1,3,1,3,2};
  const int l3s[8]={0,0,1,1,1,2,2,2};
  const int offs[9]={CG110,CG220,CG121,CG211,CG231,CG112,CG132,CG222,CGTOT};
  int t=0;
  for(int u=0;u<8;u++){ if(tid>=offs[u] && tid<offs[u+1]){ t=u; break; } }
  int l1=l1s[t], l2=l2s[t], l3=l3s[t];
  int rem = tid - offs[t];
  int d3=2*l3+1, d2=2*l2+1;
  int k = rem % d3; int j = (rem/d3)%d2; int i = rem/(d3*d2);
  cgbuf[tid] = real_cg_elem(l1,l2,l3,i,j,k);
}

// ---------------- Wm3 transpose: (64,832) -> (832,64) ----------------
__global__ void transpose_wm3_kernel(const float* __restrict__ Wm3, float* __restrict__ Wm3T){
  int t = blockIdx.x*256 + threadIdx.x;
  if(t < 64*832){ int k=t/832, c=t-832*k; Wm3T[c*64+k]=Wm3[t]; }
}

// ---------------- node linears: g (Wu) and sc (Wsc), packed [g0|g1(f,3)|g2(f,5)] ----------------
__global__ __launch_bounds__(256) void node_linear_kernel(
    const float* __restrict__ node_feats, const int* __restrict__ specie,
    const float* __restrict__ Wsc0, const float* __restrict__ Wsc1, const float* __restrict__ Wsc2,
    const float* __restrict__ Wu0,  const float* __restrict__ Wu1,  const float* __restrict__ Wu2,
    float* __restrict__ g_packed, float* __restrict__ sc_packed, int N)
{
  __shared__ float feat[576];
  int n = blockIdx.x; if(n>=N) return;
  const float4* src = (const float4*)(node_feats + (size_t)n*576);
  float4* fd = (float4*)feat;
  for(int i=threadIdx.x;i<144;i+=256) fd[i]=src[i];
  __syncthreads();
  int sp = specie[n];
  const float inv_f = 0.125f;   // 1/sqrt(64)
  for(int o=threadIdx.x; o<1152; o+=256){
    int isSc = (o>=576);
    int p = o - (isSc?576:0);
    float acc=0.f;
    if(p<64){
      const float* W = isSc ? (Wsc0 + (size_t)sp*4096) : Wu0;
      #pragma unroll 8
      for(int f=0; f<64; f++) acc += feat[f]*W[f*64+p];
    } else if(p<256){
      int q=p-64; int f=q/3, c=q-3*f;
      const float* W = isSc ? (Wsc1 + (size_t)sp*4096) : Wu1;
      #pragma unroll 8
      for(int fp=0; fp<64; fp++) acc += feat[64+3*fp+c]*W[fp*64+f];
    } else {
      int q=p-256; int f=q/5, c=q-5*f;
      const float* W = isSc ? (Wsc2 + (size_t)sp*4096) : Wu2;
      #pragma unroll 8
      for(int fp=0; fp<64; fp++) acc += feat[256+5*fp+c]*W[fp*64+f];
    }
    float* dst = isSc ? sc_packed : g_packed;
    dst[(size_t)n*576 + p] = acc*inv_f;
  }
}

// ---------------- CSR build ----------------
__global__ void count_kernel(const int* __restrict__ recv, int* __restrict__ counts, int E){
  int e = blockIdx.x*256 + threadIdx.x;
  if(e<E) atomicAdd(&counts[recv[e]],1);
}

__global__ __launch_bounds__(1024) void scan_kernel(const int* __restrict__ counts,
                                                    int* __restrict__ offsets,
                                                    int* __restrict__ cursor, int n){
  __shared__ int tmp[1024];
  int tid = threadIdx.x;
  int per = (n + 1023)/1024;
  int base = tid*per;
  int s = 0;
  for(int i=0;i<per;i++){ int idx=base+i; if(idx<n) s += counts[idx]; }
  tmp[tid]=s; __syncthreads();
  for(int off=1; off<1024; off<<=1){
    int v = (tid>=off)? tmp[tid-off] : 0;
    __syncthreads();
    tmp[tid]+=v;
    __syncthreads();
  }
  int run = (tid==0)? 0 : tmp[tid-1];
  for(int i=0;i<per;i++){
    int idx=base+i;
    if(idx<n){ offsets[idx]=run; cursor[idx]=run; run += counts[idx]; }
  }
  if(tid==1023) offsets[n]=tmp[1023];
}

__global__ void scatter_kernel(const int* __restrict__ recv, int* __restrict__ cursor,
                               int* __restrict__ edge_list, int E){
  int e = blockIdx.x*256 + threadIdx.x;
  if(e<E){ int pos=atomicAdd(&cursor[recv[e]],1); edge_list[pos]=e; }
}

// ---------------- main per-receiver aggregation (recompute messages, no atomics) ----------------
__global__ __launch_bounds__(256) void aggregate_kernel(
  const float* __restrict__ vectors, const int* __restrict__ senders,
  const int* __restrict__ edge_list, const int* __restrict__ offsets,
  const float* __restrict__ g_packed,
  const float* __restrict__ Wm1, const float* __restrict__ Wm2, const float* __restrict__ Wm3T,
  const float* __restrict__ cgbuf, float* __restrict__ a_packed, int N)
{
  __shared__ float cgs[512];
  __shared__ float acc[2752];
  __shared__ float sfeat[EC][576];
  __shared__ float sh_s[EC][16];
  __shared__ float rad_s[EC][8];
  __shared__ float h1_s[EC][64];
  __shared__ float h2_s[EC][64];
  __shared__ float mix_s[EC][832];
  __shared__ int   es_idx[EC];

  int n = blockIdx.x; if(n>=N) return;
  int tid=threadIdx.x;
  for(int i=tid;i<512;i+=256) cgs[i] = (i<CGTOT)? cgbuf[i] : 0.f;
  for(int i=tid;i<2752;i+=256) acc[i]=0.f;
  int e0 = offsets[n], e1 = offsets[n+1];

  for(int cb=e0; cb<e1; cb+=EC){
    int ec = min(EC, e1-cb);
    __syncthreads();              // protect LDS from previous chunk / init
    // ---- geometry: one thread per edge ----
    if(tid<ec){
      int e = edge_list[cb+tid];
      es_idx[tid] = senders[e];
      float vx=vectors[e*3], vy=vectors[e*3+1], vz=vectors[e*3+2];
      float x2 = vx*vx+vy*vy+vz*vz;
      float x  = sqrtf(fmaxf(x2, 1e-12f));
      float inv= 1.f/x;
      float ux=vx*inv, uy=vy*inv, uz=vz*inv;
      float env = 0.f;
      if(x<1.f){
        float x3=x*x*x; float x6=x3*x3; float x7=x6*x; float x8=x7*x;
        env = 1.f-28.f*x6+48.f*x7-21.f*x8;
      }
      #pragma unroll
      for(int nn=1;nn<=8;nn++)
        rad_s[tid][nn-1] = 1.4142135623730951f * sinf(3.14159265358979323846f*(float)nn*x)*inv*env;
      const float s3=1.7320508075688772f;
      sh_s[tid][0]=s3*uy; sh_s[tid][1]=s3*uz; sh_s[tid][2]=s3*ux;
      const float s15=3.872983346207417f, s5=2.23606797749979f;
      sh_s[tid][3]=s15*ux*uy; sh_s[tid][4]=s15*uy*uz;
      sh_s[tid][5]=0.5f*s5*(3.f*uz*uz-1.f);
      sh_s[tid][6]=s15*ux*uz; sh_s[tid][7]=0.5f*s15*(ux*ux-uy*uy);
      const float c35=2.091650066335189f, c105=10.246950765959598f;
      const float c21=1.620185174601965f, c7=1.3228756555322954f;
      sh_s[tid][8] =c35*uy*(3.f*ux*ux-uy*uy);
      sh_s[tid][9] =c105*ux*uy*uz;
      sh_s[tid][10]=c21*uy*(5.f*uz*uz-1.f);
      sh_s[tid][11]=c7*uz*(5.f*uz*uz-3.f);
      sh_s[tid][12]=c21*ux*(5.f*uz*uz-1.f);
      sh_s[tid][13]=0.5f*c105*uz*(ux*ux-uy*uy);
      sh_s[tid][14]=c35*ux*(ux*ux-3.f*uy*uy);
      sh_s[tid][15]=0.f;
    }
    __syncthreads();
    // ---- gather sender features (float4 coalesced) ----
    {
      int tot = ec*144;
      for(int i=tid;i<tot;i+=256){
        int le=i/144, w=i-144*le;
        ((float4*)sfeat[le])[w] = ((const float4*)(g_packed + (size_t)es_idx[le]*576))[w];
      }
    }
    // ---- radial MLP h1 ----
    for(int t=tid; t<EC*64; t+=256){
      int le=t>>6, j=t&63;
      float a=0.f;
      #pragma unroll
      for(int i=0;i<8;i++) a += rad_s[le][i]*Wm1[i*64+j];
      a *= 0.3535533905932738f;            // 1/sqrt(8)
      h1_s[le][j] = (le<ec)? a/(1.f+expf(-a)) : 0.f;
    }
    __syncthreads();
    // ---- h2 ----
    for(int t=tid; t<EC*64; t+=256){
      int le=t>>6, j=t&63;
      float a=0.f;
      #pragma unroll 8
      for(int i=0;i<64;i++) a += h1_s[le][i]*Wm2[i*64+j];
      a *= 0.125f;                          // 1/sqrt(64)
      h2_s[le][j] = (le<ec)? a/(1.f+expf(-a)) : 0.f;
    }
    __syncthreads();
    // ---- mix = h2 @ Wm3 / 8 ; weight streamed once per chunk, reused across EC edges ----
    for(int col=tid; col<832; col+=256){
      float partial[EC];
      #pragma unroll
      for(int le=0;le<EC;le++) partial[le]=0.f;
      const float4* wt=(const float4*)(Wm3T + col*64);
      #pragma unroll 4
      for(int i=0;i<16;i++){
        float4 w=wt[i];
        #pragma unroll
        for(int le=0; le<EC; le++){
          partial[le] += h2_s[le][4*i]*w.x + h2_s[le][4*i+1]*w.y
                       + h2_s[le][4*i+2]*w.z + h2_s[le][4*i+3]*w.w;
        }
      }
      #pragma unroll
      for(int le=0;le<EC;le++) mix_s[le][col]=partial[le]*0.125f;
    }
    __syncthreads();
    // ---- accumulate messages: one task per (m-row), all components per task ----
    for(int t=tid; t<832; t+=256){
      if(t<192){
        int part=t>>6, f=t&63;
        float racc=0.f;
        for(int le=0; le<ec; le++){
          const float* s=sfeat[le]; const float* sh=sh_s[le];
          float base;
          if(part==0) base = s[f];
          else if(part==1){
            base=0.f;
            #pragma unroll
            for(int i=0;i<3;i++){ float si=s[64+3*f+i];
              #pragma unroll
              for(int j=0;j<3;j++) base += si*sh[j]*cgs[CG110+i*3+j]; }
          } else {
            base=0.f;
            #pragma unroll
            for(int i=0;i<5;i++){ float si=s[256+5*f+i];
              #pragma unroll
              for(int j=0;j<5;j++) base += si*sh[3+j]*cgs[CG220+i*5+j]; }
          }
          racc += base*mix_s[le][t];
        }
        acc[t] += racc;
      } else if(t<512){
        int mrow=t-192; int part=mrow>>6, f=mrow&63;
        float r0=0.f,r1=0.f,r2=0.f;
        for(int le=0; le<ec; le++){
          const float* s=sfeat[le]; const float* sh=sh_s[le];
          float b0=0.f,b1=0.f,b2=0.f;
          if(part==0){ b0=s[64+3*f]; b1=s[64+3*f+1]; b2=s[64+3*f+2]; }
          else if(part==1){ float v=s[f]; b0=v*sh[0]; b1=v*sh[1]; b2=v*sh[2]; }
          else if(part==2){
            #pragma unroll
            for(int i=0;i<3;i++){ float si=s[64+3*f+i];
              #pragma unroll
              for(int j=0;j<5;j++){ float p=si*sh[3+j]; const float* cc=&cgs[CG121+(i*5+j)*3];
                b0+=p*cc[0]; b1+=p*cc[1]; b2+=p*cc[2]; } }
          } else if(part==3){
            #pragma unroll
            for(int i=0;i<5;i++){ float si=s[256+5*f+i];
              #pragma unroll
              for(int j=0;j<3;j++){ float p=si*sh[j]; const float* cc=&cgs[CG211+(i*3+j)*3];
                b0+=p*cc[0]; b1+=p*cc[1]; b2+=p*cc[2]; } }
          } else {
            #pragma unroll
            for(int i=0;i<5;i++){ float si=s[256+5*f+i];
              #pragma unroll
              for(int j=0;j<7;j++){ float p=si*sh[8+j]; const float* cc=&cgs[CG231+(i*7+j)*3];
                b0+=p*cc[0]; b1+=p*cc[1]; b2+=p*cc[2]; } }
          }
          float mv=mix_s[le][192+mrow];
          r0+=b0*mv; r1+=b1*mv; r2+=b2*mv;
        }
        int qb=192+mrow*3;
        acc[qb]+=r0; acc[qb+1]+=r1; acc[qb+2]+=r2;
      } else {
        int mrow=t-512; int part=mrow>>6, f=mrow&63;
        float r0=0.f,r1=0.f,r2=0.f,r3=0.f,r4=0.f;
        for(int le=0; le<ec; le++){
          const float* s=sfeat[le]; const float* sh=sh_s[le];
          float b0=0.f,b1=0.f,b2=0.f,b3=0.f,b4=0.f;
          if(part==0){ b0=s[256+5*f]; b1=s[256+5*f+1]; b2=s[256+5*f+2]; b3=s[256+5*f+3]; b4=s[256+5*f+4]; }
          else if(part==1){ float v=s[f]; b0=v*sh[3]; b1=v*sh[4]; b2=v*sh[5]; b3=v*sh[6]; b4=v*sh[7]; }
          else if(part==2){
            #pragma unroll
            for(int i=0;i<3;i++){ float si=s[64+3*f+i];
              #pragma unroll
              for(int j=0;j<3;j++){ float p=si*sh[j]; const float* cc=&cgs[CG112+(i*3+j)*5];
                b0+=p*cc[0]; b1+=p*cc[1]; b2+=p*cc[2]; b3+=p*cc[3]; b4+=p*cc[4]; } }
          } else if(part==3){
            #pragma unroll
            for(int i=0;i<3;i++){ float si=s[64+3*f+i];
              #pragma unroll
              for(int j=0;j<7;j++){ float p=si*sh[8+j]; const float* cc=&cgs[CG132+(i*7+j)*5];
                b0+=p*cc[0]; b1+=p*cc[1]; b2+=p*cc[2]; b3+=p*cc[3]; b4+=p*cc[4]; } }
          } else {
            #pragma unroll
            for(int i=0;i<5;i++){ float si=s[256+5*f+i];
              #pragma unroll
              for(int j=0;j<5;j++){ float p=si*sh[3+j]; const float* cc=&cgs[CG222+(i*5+j)*5];
                b0+=p*cc[0]; b1+=p*cc[1]; b2+=p*cc[2]; b3+=p*cc[3]; b4+=p*cc[4]; } }
          }
          float mv=mix_s[le][512+mrow];
          r0+=b0*mv; r1+=b1*mv; r2+=b2*mv; r3+=b3*mv; r4+=b4*mv;
        }
        int qb=1152+mrow*5;
        acc[qb]+=r0; acc[qb+1]+=r1; acc[qb+2]+=r2; acc[qb+3]+=r3; acc[qb+4]+=r4;
      }
    }
  }
  __syncthreads();
  const float inv_avg = 0.31622776601683794f;   // 1/sqrt(10)
  for(int i=tid;i<2752;i+=256)
    a_packed[(size_t)n*2752+i] = acc[i]*inv_avg;
}

// ---------------- output: d0/d1/d2 GEMMs + gated epilogue + self-connection ----------------
__global__ __launch_bounds__(256) void output_kernel(
  const float* __restrict__ a_packed, const float* __restrict__ sc_packed,
  const float* __restrict__ Wd0, const float* __restrict__ Wd1, const float* __restrict__ Wd2,
  float* __restrict__ out, int N)
{
  __shared__ float aL[4][2752];
  __shared__ float dL[4][704];   // [0,192) d0 ; [192,384) d1(f,3) ; [384,704) d2(f,5)
  __shared__ float scL[4][576];
  int n0 = blockIdx.x*4;
  int tid=threadIdx.x;
  int nvalid = N-n0; if(nvalid>4) nvalid=4; if(nvalid<=0) return;
  for(int t=0;t<nvalid;t++){
    int n=n0+t;
    const float4* src=(const float4*)(a_packed+(size_t)n*2752);
    for(int i=tid;i<688;i+=256) ((float4*)aL[t])[i]=src[i];
    const float4* s2=(const float4*)(sc_packed+(size_t)n*576);
    for(int i=tid;i<144;i+=256) ((float4*)scL[t])[i]=s2[i];
  }
  __syncthreads();
  // d0
  for(int t=tid; t<nvalid*192; t+=256){
    int nn=t/192, j=t-192*nn;
    const float* a0=aL[nn];
    float s=0.f;
    #pragma unroll 8
    for(int k=0;k<192;k++) s += a0[k]*Wd0[k*192+j];
    dL[nn][j] = s * 0.07216878364870323f;     // 1/sqrt(192)
  }
  // d1
  for(int t=tid; t<nvalid*192; t+=256){
    int nn=t/192, r=t-192*nn; int f=r/3, c=r-3*f;
    const float* a1=aL[nn]+192;
    float s=0.f;
    #pragma unroll 8
    for(int m=0;m<320;m++) s += a1[m*3+c]*Wd1[m*64+f];
    dL[nn][192+r] = s*0.05590169943749474f;   // 1/sqrt(320)
  }
  // d2
  for(int t=tid; t<nvalid*320; t+=256){
    int nn=t/320, r=t-320*nn; int f=r/5, c=r-5*f;
    const float* a2=aL[nn]+1152;
    float s=0.f;
    #pragma unroll 8
    for(int m=0;m<320;m++) s += a2[m*5+c]*Wd2[m*64+f];
    dL[nn][384+r] = s*0.05590169943749474f;
  }
  __syncthreads();
  for(int t=tid;t<nvalid*576;t+=256){
    int nn=t/576, p=t-576*nn;
    int n=n0+nn;
    float v;
    if(p<64){
      float d=dL[nn][p]; v = d/(1.f+expf(-d)) + scL[nn][p];
    } else if(p<256){
      int r=p-64; int f=r/3;
      float g=dL[nn][64+f]; g=g/(1.f+expf(-g));
      v = dL[nn][192+r]*g + scL[nn][p];
    } else {
      int r=p-256; int f=r/5;
      float g=dL[nn][128+f]; g=g/(1.f+expf(-g));
      v = dL[nn][384+r]*g + scL[nn][p];
    }
    out[(size_t)n*576+p]=v;
  }
}

// ---------------- host ----------------
extern "C" void kernel_launch(void* const* d_in, const int* in_sizes, int n_in,
                              void* d_out, int out_size, void* d_ws, size_t ws_size,
                              hipStream_t stream)
{
  const float* vectors    =(const float*)d_in[0];
  const float* node_feats =(const float*)d_in[1];
  const int*   node_specie=(const int*)  d_in[2];
  const int*   senders    =(const int*)  d_in[3];
  const int*   receivers  =(const int*)  d_in[4];
  const float* Wsc0=(const float*)d_in[5];
  const float* Wsc1=(const float*)d_in[6];
  const float* Wsc2=(const float*)d_in[7];
  const float* Wu0 =(const float*)d_in[8];
  const float* Wu1 =(const float*)d_in[9];
  const float* Wu2 =(const float*)d_in[10];
  const float* Wm1 =(const float*)d_in[11];
  const float* Wm2 =(const float*)d_in[12];
  const float* Wm3 =(const float*)d_in[13];
  const float* Wd0 =(const float*)d_in[14];
  const float* Wd1 =(const float*)d_in[15];
  const float* Wd2 =(const float*)d_in[16];
  float* out = (float*)d_out;

  int E = in_sizes[0]/3;
  int N = in_sizes[1]/576;

  // workspace carve (16B aligned pieces)
  float* cgbuf     = (float*)d_ws;                         // 512
  float* g_packed  = cgbuf + 512;                          // N*576
  float* sc_packed = g_packed  + (size_t)N*576;            // N*576
  float* Wm3T      = sc_packed + (size_t)N*576;            // 832*64
  float* a_packed  = Wm3T + 832*64;                        // N*2752
  int*   counts    = (int*)(a_packed + (size_t)N*2752);    // N
  int*   offsets   = counts + N;                           // N+1
  int*   cursor    = offsets + (N+1);                      // N
  int*   edge_list = cursor + N;                           // E

  hipMemsetAsync(counts, 0, (size_t)N*sizeof(int), stream);
  cg_init_kernel<<<2,256,0,stream>>>(cgbuf);
  transpose_wm3_kernel<<<(64*832+255)/256,256,0,stream>>>(Wm3, Wm3T);
  node_linear_kernel<<<N,256,0,stream>>>(node_feats,node_specie,Wsc0,Wsc1,Wsc2,Wu0,Wu1,Wu2,
                                         g_packed,sc_packed,N);
  count_kernel<<<(E+255)/256,256,0,stream>>>(receivers,counts,E);
  scan_kernel<<<1,1024,0,stream>>>(counts,offsets,cursor,N);
  scatter_kernel<<<(E+255)/256,256,0,stream>>>(receivers,cursor,edge_list,E);
  aggregate_kernel<<<N,256,0,stream>>>(vectors,senders,edge_list,offsets,g_packed,
                                       Wm1,Wm2,Wm3T,cgbuf,a_packed,N);
  output_kernel<<<(N+3)/4,256,0,stream>>>(a_packed,sc_packed,Wd0,Wd1,Wd2,out,N);
}

// Round 2
// 852.441 us; speedup vs baseline: 1.6759x; 1.6759x over previous
//
#include <hip/hip_runtime.h>
#include <math.h>

#define EPB 8           // edges per block in edge_msg kernel

// CG tensor offsets inside cg buffer (floats)
#define CG110 0
#define CG220 9
#define CG121 34
#define CG211 79
#define CG231 124
#define CG112 229
#define CG132 274
#define CG222 379
#define CGTOT 504

// ---------------- CG coefficient init (device, double precision) ----------------
__device__ double dfact(int n){ double r=1.0; for(int i=2;i<=n;i++) r*=(double)i; return r; }

__device__ double cg_coeff(int j1,int m1,int j2,int m2,int j3,int m3){
  if(m1+m2!=m3) return 0.0;
  int lo = j1>j2 ? j1-j2 : j2-j1;
  if(j3 < lo || j3 > j1+j2) return 0.0;
  double pref = sqrt((double)(2*j3+1)*dfact(j3+j1-j2)*dfact(j3-j1+j2)*dfact(j1+j2-j3)/dfact(j1+j2+j3+1));
  pref *= sqrt(dfact(j3+m3)*dfact(j3-m3)*dfact(j1-m1)*dfact(j1+m1)*dfact(j2-m2)*dfact(j2+m2));
  double s=0.0;
  for(int k=0;k<=j1+j2+j3;k++){
    int d0=j1+j2-j3-k, d1=j1-m1-k, d2=j2+m2-k, d3=j3-j2+m1+k, d4=j3-j1-m2+k;
    if(d0<0||d1<0||d2<0||d3<0||d4<0) continue;
    double term = 1.0/(dfact(k)*dfact(d0)*dfact(d1)*dfact(d2)*dfact(d3)*dfact(d4));
    s += (k&1)? -term : term;
  }
  return pref*s;
}

__device__ void u_elem(int l,int i,int a,double& re,double& im){
  const double s=0.70710678118654752440;
  re=0.0; im=0.0;
  int mi=i-l, ma=a-l;
  if(mi==0){ if(ma==0) re=1.0; }
  else if(mi>0){ if(ma==mi) re=(mi&1)?-s:s; else if(ma==-mi) re=s; }
  else { int m=-mi; if(ma==mi) im=s; else if(ma==-mi) im=(m&1)?s:-s; }
}

__device__ float real_cg_elem(int l1,int l2,int l3,int ii,int jj,int kk){
  double acc=0.0;
  int alist[2]={ii, 2*l1-ii}; int na=(alist[1]==alist[0])?1:2;
  int blist[2]={jj, 2*l2-jj}; int nb=(blist[1]==blist[0])?1:2;
  int clist[2]={kk, 2*l3-kk}; int nc=(clist[1]==clist[0])?1:2;
  for(int ai=0;ai<na;ai++) for(int bi=0;bi<nb;bi++) for(int ci=0;ci<nc;ci++){
    int a=alist[ai], b=blist[bi], c=clist[ci];
    double w = cg_coeff(l1,a-l1,l2,b-l2,l3,c-l3);
    if(w==0.0) continue;
    double u1r,u1i,u2r,u2i,u3r,u3i;
    u_elem(l1,ii,a,u1r,u1i); u_elem(l2,jj,b,u2r,u2i); u_elem(l3,kk,c,u3r,u3i);
    double ar = u1r*u2r - u1i*u2i;
    double aiv= u1r*u2i + u1i*u2r;
    acc += (ar*u3r + aiv*u3i)*w;
  }
  return (float)acc;
}

__global__ void cg_init_kernel(float* __restrict__ cgbuf){
  int tid = blockIdx.x*blockDim.x + threadIdx.x;
  if(tid>=CGTOT) return;
  const int l1s[8]={1,2,1,2,2,1,1,2};
  const int l2s[8]={1,2,2,1,3,1,3,2};
  const int l3s[8]={0,0,1,1,1,2,2,2};
  const int offs[9]={CG110,CG220,CG121,CG211,CG231,CG112,CG132,CG222,CGTOT};
  int t=0;
  for(int u=0;u<8;u++){ if(tid>=offs[u] && tid<offs[u+1]){ t=u; break; } }
  int l1=l1s[t], l2=l2s[t], l3=l3s[t];
  int rem = tid - offs[t];
  int d3=2*l3+1, d2=2*l2+1;
  int k = rem % d3; int j = (rem/d3)%d2; int i = rem/(d3*d2);
  cgbuf[tid] = real_cg_elem(l1,l2,l3,i,j,k);
}

// ---------------- Wm3 transpose: (64,832) -> (832,64) ----------------
__global__ void transpose_wm3_kernel(const float* __restrict__ Wm3, float* __restrict__ Wm3T){
  int t = blockIdx.x*256 + threadIdx.x;
  if(t < 64*832){ int k=t/832, c=t-832*k; Wm3T[c*64+k]=Wm3[t]; }
}

// ---------------- node linears ----------------
__global__ __launch_bounds__(256) void node_linear_kernel(
    const float* __restrict__ node_feats, const int* __restrict__ specie,
    const float* __restrict__ Wsc0, const float* __restrict__ Wsc1, const float* __restrict__ Wsc2,
    const float* __restrict__ Wu0,  const float* __restrict__ Wu1,  const float* __restrict__ Wu2,
    float* __restrict__ g_packed, float* __restrict__ sc_packed, int N)
{
  __shared__ float feat[576];
  int n = blockIdx.x; if(n>=N) return;
  const float4* src = (const float4*)(node_feats + (size_t)n*576);
  float4* fd = (float4*)feat;
  for(int i=threadIdx.x;i<144;i+=256) fd[i]=src[i];
  __syncthreads();
  int sp = specie[n];
  const float inv_f = 0.125f;
  for(int o=threadIdx.x; o<1152; o+=256){
    int isSc = (o>=576);
    int p = o - (isSc?576:0);
    float acc=0.f;
    if(p<64){
      const float* W = isSc ? (Wsc0 + (size_t)sp*4096) : Wu0;
      #pragma unroll 8
      for(int f=0; f<64; f++) acc += feat[f]*W[f*64+p];
    } else if(p<256){
      int q=p-64; int f=q/3, c=q-3*f;
      const float* W = isSc ? (Wsc1 + (size_t)sp*4096) : Wu1;
      #pragma unroll 8
      for(int fp=0; fp<64; fp++) acc += feat[64+3*fp+c]*W[fp*64+f];
    } else {
      int q=p-256; int f=q/5, c=q-5*f;
      const float* W = isSc ? (Wsc2 + (size_t)sp*4096) : Wu2;
      #pragma unroll 8
      for(int fp=0; fp<64; fp++) acc += feat[256+5*fp+c]*W[fp*64+f];
    }
    float* dst = isSc ? sc_packed : g_packed;
    dst[(size_t)n*576 + p] = acc*inv_f;
  }
}

// ---------------- CSR build ----------------
__global__ void count_kernel(const int* __restrict__ recv, int* __restrict__ counts, int E){
  int e = blockIdx.x*256 + threadIdx.x;
  if(e<E) atomicAdd(&counts[recv[e]],1);
}

__global__ __launch_bounds__(1024) void scan_kernel(const int* __restrict__ counts,
                                                    int* __restrict__ offsets,
                                                    int* __restrict__ cursor, int n){
  __shared__ int tmp[1024];
  int tid = threadIdx.x;
  int per = (n + 1023)/1024;
  int base = tid*per;
  int s = 0;
  for(int i=0;i<per;i++){ int idx=base+i; if(idx<n) s += counts[idx]; }
  tmp[tid]=s; __syncthreads();
  for(int off=1; off<1024; off<<=1){
    int v = (tid>=off)? tmp[tid-off] : 0;
    __syncthreads();
    tmp[tid]+=v;
    __syncthreads();
  }
  int run = (tid==0)? 0 : tmp[tid-1];
  for(int i=0;i<per;i++){
    int idx=base+i;
    if(idx<n){ offsets[idx]=run; cursor[idx]=run; run += counts[idx]; }
  }
  if(tid==1023) offsets[n]=tmp[1023];
}

__global__ void scatter_kernel(const int* __restrict__ recv, int* __restrict__ cursor,
                               int* __restrict__ edge_list, int E){
  int e = blockIdx.x*256 + threadIdx.x;
  if(e<E){ int pos=atomicAdd(&cursor[recv[e]],1); edge_list[pos]=e; }
}

// ---------------- Phase A: per-edge messages, written in CSR order ----------------
// wtab layout per edge (102 floats):
//  [0,3)   W110[i]         [3,8)   W220[i]
//  [8,17)  W121[i*3+c]     [17,32) W211[i*3+c]   [32,47) W231[i*3+c]
//  [47,62) W112[i*5+c]     [62,77) W132[i*5+c]   [77,102) W222[i*5+c]
__global__ __launch_bounds__(256) void edge_msg_kernel(
  const float* __restrict__ vectors, const int* __restrict__ senders,
  const int* __restrict__ edge_list,
  const float* __restrict__ g_packed,
  const float* __restrict__ Wm1, const float* __restrict__ Wm2, const float* __restrict__ Wm3T,
  const float* __restrict__ cgbuf, float* __restrict__ msg, int posLo, int posHi)
{
  __shared__ float cgs[504];
  __shared__ float sh_s[EPB][16];
  __shared__ float rad_s[EPB][8];
  __shared__ float h1_s[EPB][64];
  __shared__ float h2_s[EPB][64];
  __shared__ float mix_s[EPB][832];
  __shared__ float wt_s[EPB][104];
  __shared__ int   sidx[EPB];

  int tid = threadIdx.x;
  int base = posLo + blockIdx.x*EPB;
  int ecnt = min(EPB, posHi - base);
  if (ecnt <= 0) return;

  for (int i=tid;i<504;i+=256) cgs[i]=cgbuf[i];

  if (tid < EPB){
    int le = tid;
    int pos = base + ((le<ecnt)? le : 0);
    int e = edge_list[pos];
    sidx[le] = senders[e];
    float vx=vectors[e*3], vy=vectors[e*3+1], vz=vectors[e*3+2];
    float x2 = vx*vx+vy*vy+vz*vz;
    float x  = sqrtf(fmaxf(x2, 1e-12f));
    float inv= 1.f/x;
    float ux=vx*inv, uy=vy*inv, uz=vz*inv;
    float env = 0.f;
    if(x<1.f){
      float x3=x*x*x; float x6=x3*x3; float x7=x6*x; float x8=x7*x;
      env = 1.f-28.f*x6+48.f*x7-21.f*x8;
    }
    #pragma unroll
    for(int nn=1;nn<=8;nn++)
      rad_s[le][nn-1] = 1.4142135623730951f * sinf(3.14159265358979323846f*(float)nn*x)*inv*env;
    const float s3=1.7320508075688772f;
    sh_s[le][0]=s3*uy; sh_s[le][1]=s3*uz; sh_s[le][2]=s3*ux;
    const float s15=3.872983346207417f, s5=2.23606797749979f;
    sh_s[le][3]=s15*ux*uy; sh_s[le][4]=s15*uy*uz;
    sh_s[le][5]=0.5f*s5*(3.f*uz*uz-1.f);
    sh_s[le][6]=s15*ux*uz; sh_s[le][7]=0.5f*s15*(ux*ux-uy*uy);
    const float c35=2.091650066335189f, c105=10.246950765959598f;
    const float c21=1.620185174601965f, c7=1.3228756555322954f;
    sh_s[le][8] =c35*uy*(3.f*ux*ux-uy*uy);
    sh_s[le][9] =c105*ux*uy*uz;
    sh_s[le][10]=c21*uy*(5.f*uz*uz-1.f);
    sh_s[le][11]=c7*uz*(5.f*uz*uz-3.f);
    sh_s[le][12]=c21*ux*(5.f*uz*uz-1.f);
    sh_s[le][13]=0.5f*c105*uz*(ux*ux-uy*uy);
    sh_s[le][14]=c35*ux*(ux*ux-3.f*uy*uy);
    sh_s[le][15]=0.f;
  }
  __syncthreads();
  // h1
  for (int t=tid; t<EPB*64; t+=256){
    int le=t>>6, j=t&63;
    float a=0.f;
    #pragma unroll
    for (int i=0;i<8;i++) a += rad_s[le][i]*Wm1[i*64+j];
    a *= 0.3535533905932738f;
    h1_s[le][j] = a/(1.f+expf(-a));
  }
  __syncthreads();
  // h2 (tasks 0..511) + wtab (tasks 512..1327) in one phase
  for (int t=tid; t<EPB*64 + EPB*102; t+=256){
    if (t < EPB*64){
      int le=t>>6, j=t&63;
      float a=0.f;
      #pragma unroll 16
      for (int i=0;i<64;i++) a += h1_s[le][i]*Wm2[i*64+j];
      a *= 0.125f;
      h2_s[le][j] = a/(1.f+expf(-a));
    } else {
      int w = t - EPB*64;
      int le = w/102, idx = w - 102*le;
      const float* sh = sh_s[le];
      float v = 0.f;
      if (idx < 3){
        int i=idx;
        #pragma unroll
        for(int j=0;j<3;j++) v += sh[j]*cgs[CG110+i*3+j];
      } else if (idx < 8){
        int i=idx-3;
        #pragma unroll
        for(int j=0;j<5;j++) v += sh[3+j]*cgs[CG220+i*5+j];
      } else if (idx < 17){
        int r=idx-8; int i=r/3, c=r-3*i;
        #pragma unroll
        for(int j=0;j<5;j++) v += sh[3+j]*cgs[CG121+(i*5+j)*3+c];
      } else if (idx < 32){
        int r=idx-17; int i=r/3, c=r-3*i;
        #pragma unroll
        for(int j=0;j<3;j++) v += sh[j]*cgs[CG211+(i*3+j)*3+c];
      } else if (idx < 47){
        int r=idx-32; int i=r/3, c=r-3*i;
        #pragma unroll
        for(int j=0;j<7;j++) v += sh[8+j]*cgs[CG231+(i*7+j)*3+c];
      } else if (idx < 62){
        int r=idx-47; int i=r/5, c=r-5*i;
        #pragma unroll
        for(int j=0;j<3;j++) v += sh[j]*cgs[CG112+(i*3+j)*5+c];
      } else if (idx < 77){
        int r=idx-62; int i=r/5, c=r-5*i;
        #pragma unroll
        for(int j=0;j<7;j++) v += sh[8+j]*cgs[CG132+(i*7+j)*5+c];
      } else {
        int r=idx-77; int i=r/5, c=r-5*i;
        #pragma unroll
        for(int j=0;j<5;j++) v += sh[3+j]*cgs[CG222+(i*5+j)*5+c];
      }
      wt_s[le][idx]=v;
    }
  }
  __syncthreads();
  // mix = h2 @ Wm3 / 8 : block-wide, Wm3T read once per block
  for (int c=tid; c<832; c+=256){
    float acc0=0.f,acc1=0.f,acc2=0.f,acc3=0.f,acc4=0.f,acc5=0.f,acc6=0.f,acc7=0.f;
    const float4* wt=(const float4*)(Wm3T + c*64);
    #pragma unroll 4
    for (int k4=0;k4<16;k4++){
      float4 w=wt[k4];
      int k=4*k4;
      acc0 += h2_s[0][k]*w.x + h2_s[0][k+1]*w.y + h2_s[0][k+2]*w.z + h2_s[0][k+3]*w.w;
      acc1 += h2_s[1][k]*w.x + h2_s[1][k+1]*w.y + h2_s[1][k+2]*w.z + h2_s[1][k+3]*w.w;
      acc2 += h2_s[2][k]*w.x + h2_s[2][k+1]*w.y + h2_s[2][k+2]*w.z + h2_s[2][k+3]*w.w;
      acc3 += h2_s[3][k]*w.x + h2_s[3][k+1]*w.y + h2_s[3][k+2]*w.z + h2_s[3][k+3]*w.w;
      acc4 += h2_s[4][k]*w.x + h2_s[4][k+1]*w.y + h2_s[4][k+2]*w.z + h2_s[4][k+3]*w.w;
      acc5 += h2_s[5][k]*w.x + h2_s[5][k+1]*w.y + h2_s[5][k+2]*w.z + h2_s[5][k+3]*w.w;
      acc6 += h2_s[6][k]*w.x + h2_s[6][k+1]*w.y + h2_s[6][k+2]*w.z + h2_s[6][k+3]*w.w;
      acc7 += h2_s[7][k]*w.x + h2_s[7][k+1]*w.y + h2_s[7][k+2]*w.z + h2_s[7][k+3]*w.w;
    }
    mix_s[0][c]=acc0*0.125f; mix_s[1][c]=acc1*0.125f;
    mix_s[2][c]=acc2*0.125f; mix_s[3][c]=acc3*0.125f;
    mix_s[4][c]=acc4*0.125f; mix_s[5][c]=acc5*0.125f;
    mix_s[6][c]=acc6*0.125f; mix_s[7][c]=acc7*0.125f;
  }
  __syncthreads();
  // message phase: wave w handles edges 2w, 2w+1; lane = feature
  {
    int wave = tid>>6, lane = tid&63;
    for (int q=0;q<2;q++){
      int le = wave*2+q;
      if (le >= ecnt) continue;
      int pos = base + le;
      const float* g = g_packed + (size_t)sidx[le]*576;
      float s0  = g[lane];
      float s10 = g[64+3*lane], s11 = g[65+3*lane], s12 = g[66+3*lane];
      float s20 = g[256+5*lane], s21 = g[257+5*lane], s22 = g[258+5*lane],
            s23 = g[259+5*lane], s24 = g[260+5*lane];
      const float* W  = wt_s[le];
      const float* sh = sh_s[le];
      const float* mx = mix_s[le];
      float* mp = msg + (size_t)(pos - posLo)*2752;
      // m0
      mp[lane]     = s0*mx[lane];
      mp[64+lane]  = (s10*W[0]+s11*W[1]+s12*W[2])*mx[64+lane];
      mp[128+lane] = (s20*W[3]+s21*W[4]+s22*W[5]+s23*W[6]+s24*W[7])*mx[128+lane];
      // m1 (3 comps per row)
      {
        float m = mx[192+lane]; int b = 192+3*lane;
        mp[b]=s10*m; mp[b+1]=s11*m; mp[b+2]=s12*m;
        m = mx[256+lane]; b = 192+(64+lane)*3;
        mp[b]=s0*sh[0]*m; mp[b+1]=s0*sh[1]*m; mp[b+2]=s0*sh[2]*m;
        m = mx[320+lane]; b = 192+(128+lane)*3;
        #pragma unroll
        for(int c=0;c<3;c++)
          mp[b+c] = (s10*W[8+c]+s11*W[11+c]+s12*W[14+c])*m;
        m = mx[384+lane]; b = 192+(192+lane)*3;
        #pragma unroll
        for(int c=0;c<3;c++)
          mp[b+c] = (s20*W[17+c]+s21*W[20+c]+s22*W[23+c]+s23*W[26+c]+s24*W[29+c])*m;
        m = mx[448+lane]; b = 192+(256+lane)*3;
        #pragma unroll
        for(int c=0;c<3;c++)
          mp[b+c] = (s20*W[32+c]+s21*W[35+c]+s22*W[38+c]+s23*W[41+c]+s24*W[44+c])*m;
      }
      // m2 (5 comps per row)
      {
        float m = mx[512+lane]; int b = 1152+5*lane;
        mp[b]=s20*m; mp[b+1]=s21*m; mp[b+2]=s22*m; mp[b+3]=s23*m; mp[b+4]=s24*m;
        m = mx[576+lane]; b = 1152+(64+lane)*5;
        #pragma unroll
        for(int c=0;c<5;c++) mp[b+c]=s0*sh[3+c]*m;
        m = mx[640+lane]; b = 1152+(128+lane)*5;
        #pragma unroll
        for(int c=0;c<5;c++)
          mp[b+c] = (s10*W[47+c]+s11*W[52+c]+s12*W[57+c])*m;
        m = mx[704+lane]; b = 1152+(192+lane)*5;
        #pragma unroll
        for(int c=0;c<5;c++)
          mp[b+c] = (s10*W[62+c]+s11*W[67+c]+s12*W[72+c])*m;
        m = mx[768+lane]; b = 1152+(256+lane)*5;
        #pragma unroll
        for(int c=0;c<5;c++)
          mp[b+c] = (s20*W[77+c]+s21*W[82+c]+s22*W[87+c]+s23*W[92+c]+s24*W[97+c])*m;
      }
    }
  }
}

// ---------------- Phase B: segment-sum of contiguous msg rows into a_packed ----------------
__global__ __launch_bounds__(256) void gather_kernel(
  const float* __restrict__ msg, const int* __restrict__ offsets,
  float* __restrict__ a_packed, int posLo, int posHi, int N)
{
  int n = blockIdx.x; if(n>=N) return;
  int e0 = offsets[n], e1 = offsets[n+1];
  if (e0 < posLo) e0 = posLo;
  if (e1 > posHi) e1 = posHi;
  if (e0 >= e1) return;
  float4* dst = (float4*)(a_packed + (size_t)n*2752);
  for (int i=threadIdx.x; i<688; i+=256){
    float4 a = dst[i];
    for (int p=e0; p<e1; p++){
      float4 v = ((const float4*)(msg + (size_t)(p-posLo)*2752))[i];
      a.x+=v.x; a.y+=v.y; a.z+=v.z; a.w+=v.w;
    }
    dst[i]=a;
  }
}

// ---------------- output: d0/d1/d2 GEMMs + gated epilogue + self-connection ----------------
__global__ __launch_bounds__(256) void output_kernel(
  const float* __restrict__ a_packed, const float* __restrict__ sc_packed,
  const float* __restrict__ Wd0, const float* __restrict__ Wd1, const float* __restrict__ Wd2,
  float* __restrict__ out, int N)
{
  __shared__ float aL[4][2752];
  __shared__ float dL[4][704];
  __shared__ float scL[4][576];
  int n0 = blockIdx.x*4;
  int tid=threadIdx.x;
  int nvalid = N-n0; if(nvalid>4) nvalid=4; if(nvalid<=0) return;
  const float inv_avg = 0.31622776601683794f;   // 1/sqrt(10)
  for(int t=0;t<nvalid;t++){
    int n=n0+t;
    const float4* src=(const float4*)(a_packed+(size_t)n*2752);
    for(int i=tid;i<688;i+=256){
      float4 v=src[i];
      v.x*=inv_avg; v.y*=inv_avg; v.z*=inv_avg; v.w*=inv_avg;
      ((float4*)aL[t])[i]=v;
    }
    const float4* s2=(const float4*)(sc_packed+(size_t)n*576);
    for(int i=tid;i<144;i+=256) ((float4*)scL[t])[i]=s2[i];
  }
  __syncthreads();
  for(int t=tid; t<nvalid*192; t+=256){
    int nn=t/192, j=t-192*nn;
    const float* a0=aL[nn];
    float s=0.f;
    #pragma unroll 8
    for(int k=0;k<192;k++) s += a0[k]*Wd0[k*192+j];
    dL[nn][j] = s * 0.07216878364870323f;     // 1/sqrt(192)
  }
  for(int t=tid; t<nvalid*192; t+=256){
    int nn=t/192, r=t-192*nn; int f=r/3, c=r-3*f;
    const float* a1=aL[nn]+192;
    float s=0.f;
    #pragma unroll 8
    for(int m=0;m<320;m++) s += a1[m*3+c]*Wd1[m*64+f];
    dL[nn][192+r] = s*0.05590169943749474f;   // 1/sqrt(320)
  }
  for(int t=tid; t<nvalid*320; t+=256){
    int nn=t/320, r=t-320*nn; int f=r/5, c=r-5*f;
    const float* a2=aL[nn]+1152;
    float s=0.f;
    #pragma unroll 8
    for(int m=0;m<320;m++) s += a2[m*5+c]*Wd2[m*64+f];
    dL[nn][384+r] = s*0.05590169943749474f;
  }
  __syncthreads();
  for(int t=tid;t<nvalid*576;t+=256){
    int nn=t/576, p=t-576*nn;
    int n=n0+nn;
    float v;
    if(p<64){
      float d=dL[nn][p]; v = d/(1.f+expf(-d)) + scL[nn][p];
    } else if(p<256){
      int r=p-64; int f=r/3;
      float g=dL[nn][64+f]; g=g/(1.f+expf(-g));
      v = dL[nn][192+r]*g + scL[nn][p];
    } else {
      int r=p-256; int f=r/5;
      float g=dL[nn][128+f]; g=g/(1.f+expf(-g));
      v = dL[nn][384+r]*g + scL[nn][p];
    }
    out[(size_t)n*576+p]=v;
  }
}

// ---------------- host ----------------
extern "C" void kernel_launch(void* const* d_in, const int* in_sizes, int n_in,
                              void* d_out, int out_size, void* d_ws, size_t ws_size,
                              hipStream_t stream)
{
  const float* vectors    =(const float*)d_in[0];
  const float* node_feats =(const float*)d_in[1];
  const int*   node_specie=(const int*)  d_in[2];
  const int*   senders    =(const int*)  d_in[3];
  const int*   receivers  =(const int*)  d_in[4];
  const float* Wsc0=(const float*)d_in[5];
  const float* Wsc1=(const float*)d_in[6];
  const float* Wsc2=(const float*)d_in[7];
  const float* Wu0 =(const float*)d_in[8];
  const float* Wu1 =(const float*)d_in[9];
  const float* Wu2 =(const float*)d_in[10];
  const float* Wm1 =(const float*)d_in[11];
  const float* Wm2 =(const float*)d_in[12];
  const float* Wm3 =(const float*)d_in[13];
  const float* Wd0 =(const float*)d_in[14];
  const float* Wd1 =(const float*)d_in[15];
  const float* Wd2 =(const float*)d_in[16];
  float* out = (float*)d_out;

  int E = in_sizes[0]/3;
  int N = in_sizes[1]/576;

  // workspace carve
  float* cgbuf     = (float*)d_ws;                         // 512
  float* g_packed  = cgbuf + 512;                          // N*576
  float* sc_packed = g_packed  + (size_t)N*576;            // N*576
  float* Wm3T      = sc_packed + (size_t)N*576;            // 832*64 = 53248
  float* a_packed  = Wm3T + 53248;                         // N*2752
  int*   counts    = (int*)(a_packed + (size_t)N*2752);    // N
  int*   offsets   = counts + N;                           // N+1
  int*   cursor    = offsets + (N+1);                      // N
  int*   edge_list = cursor + N;                           // E
  size_t used_bytes = (size_t)((char*)(edge_list + E) - (char*)d_ws);
  used_bytes = (used_bytes + 255) & ~(size_t)255;
  float* msg = (float*)((char*)d_ws + used_bytes);
  size_t avail = (ws_size > used_bytes) ? (ws_size - used_bytes) : 0;
  long long cap = (long long)(avail / (2752u*4u));
  if (cap > E) cap = E;
  cap = (cap/EPB)*EPB;
  if (cap < EPB) cap = EPB;   // ws too small would be fatal anyway

  hipMemsetAsync(counts, 0, (size_t)N*sizeof(int), stream);
  hipMemsetAsync(a_packed, 0, (size_t)N*2752*sizeof(float), stream);
  cg_init_kernel<<<2,256,0,stream>>>(cgbuf);
  transpose_wm3_kernel<<<(64*832+255)/256,256,0,stream>>>(Wm3, Wm3T);
  node_linear_kernel<<<N,256,0,stream>>>(node_feats,node_specie,Wsc0,Wsc1,Wsc2,Wu0,Wu1,Wu2,
                                         g_packed,sc_packed,N);
  count_kernel<<<(E+255)/256,256,0,stream>>>(receivers,counts,E);
  scan_kernel<<<1,1024,0,stream>>>(counts,offsets,cursor,N);
  scatter_kernel<<<(E+255)/256,256,0,stream>>>(receivers,cursor,edge_list,E);

  for (long long lo=0; lo<E; lo+=cap){
    long long hi = lo + cap; if (hi > E) hi = E;
    int cnt = (int)(hi - lo);
    int blocks = (cnt + EPB - 1)/EPB;
    edge_msg_kernel<<<blocks,256,0,stream>>>(vectors,senders,edge_list,g_packed,
                                             Wm1,Wm2,Wm3T,cgbuf,msg,(int)lo,(int)hi);
    gather_kernel<<<N,256,0,stream>>>(msg,offsets,a_packed,(int)lo,(int)hi,N);
  }

  output_kernel<<<(N+3)/4,256,0,stream>>>(a_packed,sc_packed,Wd0,Wd1,Wd2,out,N);
}

// Round 3
// 717.608 us; speedup vs baseline: 1.9908x; 1.1879x over previous
//
#include <hip/hip_runtime.h>
#include <math.h>

#define EPB 8           // edges per block in edge_msg kernel

// CG tensor offsets inside cg buffer (floats)
#define CG110 0
#define CG220 9
#define CG121 34
#define CG211 79
#define CG231 124
#define CG112 229
#define CG132 274
#define CG222 379
#define CGTOT 504

// ---------------- CG coefficient init (device, double precision) ----------------
__device__ double dfact(int n){ double r=1.0; for(int i=2;i<=n;i++) r*=(double)i; return r; }

__device__ double cg_coeff(int j1,int m1,int j2,int m2,int j3,int m3){
  if(m1+m2!=m3) return 0.0;
  int lo = j1>j2 ? j1-j2 : j2-j1;
  if(j3 < lo || j3 > j1+j2) return 0.0;
  double pref = sqrt((double)(2*j3+1)*dfact(j3+j1-j2)*dfact(j3-j1+j2)*dfact(j1+j2-j3)/dfact(j1+j2+j3+1));
  pref *= sqrt(dfact(j3+m3)*dfact(j3-m3)*dfact(j1-m1)*dfact(j1+m1)*dfact(j2-m2)*dfact(j2+m2));
  double s=0.0;
  for(int k=0;k<=j1+j2+j3;k++){
    int d0=j1+j2-j3-k, d1=j1-m1-k, d2=j2+m2-k, d3=j3-j2+m1+k, d4=j3-j1-m2+k;
    if(d0<0||d1<0||d2<0||d3<0||d4<0) continue;
    double term = 1.0/(dfact(k)*dfact(d0)*dfact(d1)*dfact(d2)*dfact(d3)*dfact(d4));
    s += (k&1)? -term : term;
  }
  return pref*s;
}

__device__ void u_elem(int l,int i,int a,double& re,double& im){
  const double s=0.70710678118654752440;
  re=0.0; im=0.0;
  int mi=i-l, ma=a-l;
  if(mi==0){ if(ma==0) re=1.0; }
  else if(mi>0){ if(ma==mi) re=(mi&1)?-s:s; else if(ma==-mi) re=s; }
  else { int m=-mi; if(ma==mi) im=s; else if(ma==-mi) im=(m&1)?s:-s; }
}

__device__ float real_cg_elem(int l1,int l2,int l3,int ii,int jj,int kk){
  double acc=0.0;
  int alist[2]={ii, 2*l1-ii}; int na=(alist[1]==alist[0])?1:2;
  int blist[2]={jj, 2*l2-jj}; int nb=(blist[1]==blist[0])?1:2;
  int clist[2]={kk, 2*l3-kk}; int nc=(clist[1]==clist[0])?1:2;
  for(int ai=0;ai<na;ai++) for(int bi=0;bi<nb;bi++) for(int ci=0;ci<nc;ci++){
    int a=alist[ai], b=blist[bi], c=clist[ci];
    double w = cg_coeff(l1,a-l1,l2,b-l2,l3,c-l3);
    if(w==0.0) continue;
    double u1r,u1i,u2r,u2i,u3r,u3i;
    u_elem(l1,ii,a,u1r,u1i); u_elem(l2,jj,b,u2r,u2i); u_elem(l3,kk,c,u3r,u3i);
    double ar = u1r*u2r - u1i*u2i;
    double aiv= u1r*u2i + u1i*u2r;
    acc += (ar*u3r + aiv*u3i)*w;
  }
  return (float)acc;
}

__global__ void cg_init_kernel(float* __restrict__ cgbuf){
  int tid = blockIdx.x*blockDim.x + threadIdx.x;
  if(tid>=CGTOT) return;
  const int l1s[8]={1,2,1,2,2,1,1,2};
  const int l2s[8]={1,2,2,1,3,1,3,2};
  const int l3s[8]={0,0,1,1,1,2,2,2};
  const int offs[9]={CG110,CG220,CG121,CG211,CG231,CG112,CG132,CG222,CGTOT};
  int t=0;
  for(int u=0;u<8;u++){ if(tid>=offs[u] && tid<offs[u+1]){ t=u; break; } }
  int l1=l1s[t], l2=l2s[t], l3=l3s[t];
  int rem = tid - offs[t];
  int d3=2*l3+1, d2=2*l2+1;
  int k = rem % d3; int j = (rem/d3)%d2; int i = rem/(d3*d2);
  cgbuf[tid] = real_cg_elem(l1,l2,l3,i,j,k);
}

// ---------------- Wm3 transpose: (64,832) -> (832,64) ----------------
__global__ void transpose_wm3_kernel(const float* __restrict__ Wm3, float* __restrict__ Wm3T){
  int t = blockIdx.x*256 + threadIdx.x;
  if(t < 64*832){ int k=t/832, c=t-832*k; Wm3T[c*64+k]=Wm3[t]; }
}

// ---------------- node linears (fallback, species-dependent) ----------------
__global__ __launch_bounds__(256) void node_linear_kernel(
    const float* __restrict__ node_feats, const int* __restrict__ specie,
    const float* __restrict__ Wsc0, const float* __restrict__ Wsc1, const float* __restrict__ Wsc2,
    const float* __restrict__ Wu0,  const float* __restrict__ Wu1,  const float* __restrict__ Wu2,
    float* __restrict__ g_packed, float* __restrict__ sc_packed, int N)
{
  __shared__ float feat[576];
  int n = blockIdx.x; if(n>=N) return;
  const float4* src = (const float4*)(node_feats + (size_t)n*576);
  float4* fd = (float4*)feat;
  for(int i=threadIdx.x;i<144;i+=256) fd[i]=src[i];
  __syncthreads();
  int sp = specie[n];
  const float inv_f = 0.125f;
  for(int o=threadIdx.x; o<1152; o+=256){
    int isSc = (o>=576);
    int p = o - (isSc?576:0);
    float acc=0.f;
    if(p<64){
      const float* W = isSc ? (Wsc0 + (size_t)sp*4096) : Wu0;
      #pragma unroll 8
      for(int f=0; f<64; f++) acc += feat[f]*W[f*64+p];
    } else if(p<256){
      int q=p-64; int f=q/3, c=q-3*f;
      const float* W = isSc ? (Wsc1 + (size_t)sp*4096) : Wu1;
      #pragma unroll 8
      for(int fp=0; fp<64; fp++) acc += feat[64+3*fp+c]*W[fp*64+f];
    } else {
      int q=p-256; int f=q/5, c=q-5*f;
      const float* W = isSc ? (Wsc2 + (size_t)sp*4096) : Wu2;
      #pragma unroll 8
      for(int fp=0; fp<64; fp++) acc += feat[256+5*fp+c]*W[fp*64+f];
    }
    float* dst = isSc ? sc_packed : g_packed;
    dst[(size_t)n*576 + p] = acc*inv_f;
  }
}

// ---------------- node linears as tiled GEMM (n_species==1 fast path) ----------------
// 18 segments: s in [0,9): dst g_packed with Wu*, s in [9,18): dst sc_packed with Wsc*.
// sub = s%9: 0 -> l=0 (K stride 1), 1..3 -> l=1 c=sub-1 (stride 3), 4..8 -> l=2 c=sub-4 (stride 5)
__global__ __launch_bounds__(256) void node_gemm_kernel(
  const float* __restrict__ node_feats,
  const float* __restrict__ Wsc0, const float* __restrict__ Wsc1, const float* __restrict__ Wsc2,
  const float* __restrict__ Wu0,  const float* __restrict__ Wu1,  const float* __restrict__ Wu2,
  float* __restrict__ g_packed, float* __restrict__ sc_packed, int N)
{
  __shared__ float As[64][17];
  __shared__ float Bs[16][64];
  int tid = threadIdx.x;
  int tx = tid & 15, ty = tid >> 4;
  int s = blockIdx.y;
  int n0 = blockIdx.x*64;

  int sub = s % 9;
  int isSc = (s >= 9);
  int abase, astride;
  const float* W;
  if (sub == 0){ abase = 0; astride = 1; W = isSc? Wsc0 : Wu0; }
  else if (sub < 4){ int c = sub-1; abase = 64+c; astride = 3; W = isSc? Wsc1 : Wu1; }
  else { int c = sub-4; abase = 256+c; astride = 5; W = isSc? Wsc2 : Wu2; }
  float* dst = isSc ? sc_packed : g_packed;

  float acc[4][4];
  #pragma unroll
  for(int i=0;i<4;i++)
    #pragma unroll
    for(int j=0;j<4;j++) acc[i][j]=0.f;

  for (int k0=0; k0<64; k0+=16){
    #pragma unroll
    for (int l=0;l<4;l++){
      int idx = tid + l*256;
      int row = idx>>4, kk = idx&15;
      int n = n0+row;
      As[row][kk] = (n<N)? node_feats[(size_t)n*576 + abase + astride*(k0+kk)] : 0.f;
    }
    #pragma unroll
    for (int l=0;l<4;l++){
      int idx = tid + l*256;
      int kk = idx>>6, j = idx&63;
      Bs[kk][j] = W[(k0+kk)*64 + j];
    }
    __syncthreads();
    #pragma unroll
    for (int kk=0; kk<16; kk++){
      float av[4];
      #pragma unroll
      for(int i=0;i<4;i++) av[i] = As[ty*4+i][kk];
      float4 bv = *(const float4*)&Bs[kk][tx*4];
      #pragma unroll
      for(int i=0;i<4;i++){
        acc[i][0] += av[i]*bv.x; acc[i][1] += av[i]*bv.y;
        acc[i][2] += av[i]*bv.z; acc[i][3] += av[i]*bv.w;
      }
    }
    __syncthreads();
  }
  const float scale = 0.125f;  // 1/sqrt(64)
  #pragma unroll
  for(int i=0;i<4;i++){
    int n = n0 + ty*4+i;
    if (n>=N) continue;
    #pragma unroll
    for(int j=0;j<4;j++){
      int f = tx*4+j;
      dst[(size_t)n*576 + abase + astride*f] = acc[i][j]*scale;
    }
  }
}

// ---------------- CSR build ----------------
__global__ void count_kernel(const int* __restrict__ recv, int* __restrict__ counts, int E){
  int e = blockIdx.x*256 + threadIdx.x;
  if(e<E) atomicAdd(&counts[recv[e]],1);
}

__global__ __launch_bounds__(1024) void scan_kernel(const int* __restrict__ counts,
                                                    int* __restrict__ offsets,
                                                    int* __restrict__ cursor, int n){
  __shared__ int tmp[1024];
  int tid = threadIdx.x;
  int per = (n + 1023)/1024;
  int base = tid*per;
  int s = 0;
  for(int i=0;i<per;i++){ int idx=base+i; if(idx<n) s += counts[idx]; }
  tmp[tid]=s; __syncthreads();
  for(int off=1; off<1024; off<<=1){
    int v = (tid>=off)? tmp[tid-off] : 0;
    __syncthreads();
    tmp[tid]+=v;
    __syncthreads();
  }
  int run = (tid==0)? 0 : tmp[tid-1];
  for(int i=0;i<per;i++){
    int idx=base+i;
    if(idx<n){ offsets[idx]=run; cursor[idx]=run; run += counts[idx]; }
  }
  if(tid==1023) offsets[n]=tmp[1023];
}

__global__ void scatter_kernel(const int* __restrict__ recv, int* __restrict__ cursor,
                               int* __restrict__ edge_list, int E){
  int e = blockIdx.x*256 + threadIdx.x;
  if(e<E){ int pos=atomicAdd(&cursor[recv[e]],1); edge_list[pos]=e; }
}

// ---------------- Phase A: per-edge messages, written in CSR order ----------------
__global__ __launch_bounds__(256) void edge_msg_kernel(
  const float* __restrict__ vectors, const int* __restrict__ senders,
  const int* __restrict__ edge_list,
  const float* __restrict__ g_packed,
  const float* __restrict__ Wm1, const float* __restrict__ Wm2, const float* __restrict__ Wm3T,
  const float* __restrict__ cgbuf, float* __restrict__ msg, int posLo, int posHi)
{
  __shared__ float cgs[504];
  __shared__ float sh_s[EPB][16];
  __shared__ float rad_s[EPB][8];
  __shared__ float h1_s[EPB][64];
  __shared__ float h2_s[EPB][64];
  __shared__ float mix_s[EPB][832];
  __shared__ float wt_s[EPB][104];
  __shared__ int   sidx[EPB];

  int tid = threadIdx.x;
  int base = posLo + blockIdx.x*EPB;
  int ecnt = min(EPB, posHi - base);
  if (ecnt <= 0) return;

  for (int i=tid;i<504;i+=256) cgs[i]=cgbuf[i];

  if (tid < EPB){
    int le = tid;
    int pos = base + ((le<ecnt)? le : 0);
    int e = edge_list[pos];
    sidx[le] = senders[e];
    float vx=vectors[e*3], vy=vectors[e*3+1], vz=vectors[e*3+2];
    float x2 = vx*vx+vy*vy+vz*vz;
    float x  = sqrtf(fmaxf(x2, 1e-12f));
    float inv= 1.f/x;
    float ux=vx*inv, uy=vy*inv, uz=vz*inv;
    float env = 0.f;
    if(x<1.f){
      float x3=x*x*x; float x6=x3*x3; float x7=x6*x; float x8=x7*x;
      env = 1.f-28.f*x6+48.f*x7-21.f*x8;
    }
    #pragma unroll
    for(int nn=1;nn<=8;nn++)
      rad_s[le][nn-1] = 1.4142135623730951f * sinf(3.14159265358979323846f*(float)nn*x)*inv*env;
    const float s3=1.7320508075688772f;
    sh_s[le][0]=s3*uy; sh_s[le][1]=s3*uz; sh_s[le][2]=s3*ux;
    const float s15=3.872983346207417f, s5=2.23606797749979f;
    sh_s[le][3]=s15*ux*uy; sh_s[le][4]=s15*uy*uz;
    sh_s[le][5]=0.5f*s5*(3.f*uz*uz-1.f);
    sh_s[le][6]=s15*ux*uz; sh_s[le][7]=0.5f*s15*(ux*ux-uy*uy);
    const float c35=2.091650066335189f, c105=10.246950765959598f;
    const float c21=1.620185174601965f, c7=1.3228756555322954f;
    sh_s[le][8] =c35*uy*(3.f*ux*ux-uy*uy);
    sh_s[le][9] =c105*ux*uy*uz;
    sh_s[le][10]=c21*uy*(5.f*uz*uz-1.f);
    sh_s[le][11]=c7*uz*(5.f*uz*uz-3.f);
    sh_s[le][12]=c21*ux*(5.f*uz*uz-1.f);
    sh_s[le][13]=0.5f*c105*uz*(ux*ux-uy*uy);
    sh_s[le][14]=c35*ux*(ux*ux-3.f*uy*uy);
    sh_s[le][15]=0.f;
  }
  __syncthreads();
  // h1
  for (int t=tid; t<EPB*64; t+=256){
    int le=t>>6, j=t&63;
    float a=0.f;
    #pragma unroll
    for (int i=0;i<8;i++) a += rad_s[le][i]*Wm1[i*64+j];
    a *= 0.3535533905932738f;
    h1_s[le][j] = a/(1.f+expf(-a));
  }
  __syncthreads();
  // h2 + wtab in one phase
  for (int t=tid; t<EPB*64 + EPB*102; t+=256){
    if (t < EPB*64){
      int le=t>>6, j=t&63;
      float a=0.f;
      #pragma unroll 16
      for (int i=0;i<64;i++) a += h1_s[le][i]*Wm2[i*64+j];
      a *= 0.125f;
      h2_s[le][j] = a/(1.f+expf(-a));
    } else {
      int w = t - EPB*64;
      int le = w/102, idx = w - 102*le;
      const float* sh = sh_s[le];
      float v = 0.f;
      if (idx < 3){
        int i=idx;
        #pragma unroll
        for(int j=0;j<3;j++) v += sh[j]*cgs[CG110+i*3+j];
      } else if (idx < 8){
        int i=idx-3;
        #pragma unroll
        for(int j=0;j<5;j++) v += sh[3+j]*cgs[CG220+i*5+j];
      } else if (idx < 17){
        int r=idx-8; int i=r/3, c=r-3*i;
        #pragma unroll
        for(int j=0;j<5;j++) v += sh[3+j]*cgs[CG121+(i*5+j)*3+c];
      } else if (idx < 32){
        int r=idx-17; int i=r/3, c=r-3*i;
        #pragma unroll
        for(int j=0;j<3;j++) v += sh[j]*cgs[CG211+(i*3+j)*3+c];
      } else if (idx < 47){
        int r=idx-32; int i=r/3, c=r-3*i;
        #pragma unroll
        for(int j=0;j<7;j++) v += sh[8+j]*cgs[CG231+(i*7+j)*3+c];
      } else if (idx < 62){
        int r=idx-47; int i=r/5, c=r-5*i;
        #pragma unroll
        for(int j=0;j<3;j++) v += sh[j]*cgs[CG112+(i*3+j)*5+c];
      } else if (idx < 77){
        int r=idx-62; int i=r/5, c=r-5*i;
        #pragma unroll
        for(int j=0;j<7;j++) v += sh[8+j]*cgs[CG132+(i*7+j)*5+c];
      } else {
        int r=idx-77; int i=r/5, c=r-5*i;
        #pragma unroll
        for(int j=0;j<5;j++) v += sh[3+j]*cgs[CG222+(i*5+j)*5+c];
      }
      wt_s[le][idx]=v;
    }
  }
  __syncthreads();
  // mix = h2 @ Wm3 / 8
  for (int c=tid; c<832; c+=256){
    float acc0=0.f,acc1=0.f,acc2=0.f,acc3=0.f,acc4=0.f,acc5=0.f,acc6=0.f,acc7=0.f;
    const float4* wt=(const float4*)(Wm3T + c*64);
    #pragma unroll 4
    for (int k4=0;k4<16;k4++){
      float4 w=wt[k4];
      int k=4*k4;
      acc0 += h2_s[0][k]*w.x + h2_s[0][k+1]*w.y + h2_s[0][k+2]*w.z + h2_s[0][k+3]*w.w;
      acc1 += h2_s[1][k]*w.x + h2_s[1][k+1]*w.y + h2_s[1][k+2]*w.z + h2_s[1][k+3]*w.w;
      acc2 += h2_s[2][k]*w.x + h2_s[2][k+1]*w.y + h2_s[2][k+2]*w.z + h2_s[2][k+3]*w.w;
      acc3 += h2_s[3][k]*w.x + h2_s[3][k+1]*w.y + h2_s[3][k+2]*w.z + h2_s[3][k+3]*w.w;
      acc4 += h2_s[4][k]*w.x + h2_s[4][k+1]*w.y + h2_s[4][k+2]*w.z + h2_s[4][k+3]*w.w;
      acc5 += h2_s[5][k]*w.x + h2_s[5][k+1]*w.y + h2_s[5][k+2]*w.z + h2_s[5][k+3]*w.w;
      acc6 += h2_s[6][k]*w.x + h2_s[6][k+1]*w.y + h2_s[6][k+2]*w.z + h2_s[6][k+3]*w.w;
      acc7 += h2_s[7][k]*w.x + h2_s[7][k+1]*w.y + h2_s[7][k+2]*w.z + h2_s[7][k+3]*w.w;
    }
    mix_s[0][c]=acc0*0.125f; mix_s[1][c]=acc1*0.125f;
    mix_s[2][c]=acc2*0.125f; mix_s[3][c]=acc3*0.125f;
    mix_s[4][c]=acc4*0.125f; mix_s[5][c]=acc5*0.125f;
    mix_s[6][c]=acc6*0.125f; mix_s[7][c]=acc7*0.125f;
  }
  __syncthreads();
  // message phase: wave w handles edges 2w, 2w+1; lane = feature
  {
    int wave = tid>>6, lane = tid&63;
    for (int q=0;q<2;q++){
      int le = wave*2+q;
      if (le >= ecnt) continue;
      int pos = base + le;
      const float* g = g_packed + (size_t)sidx[le]*576;
      float s0  = g[lane];
      float s10 = g[64+3*lane], s11 = g[65+3*lane], s12 = g[66+3*lane];
      float s20 = g[256+5*lane], s21 = g[257+5*lane], s22 = g[258+5*lane],
            s23 = g[259+5*lane], s24 = g[260+5*lane];
      const float* W  = wt_s[le];
      const float* sh = sh_s[le];
      const float* mx = mix_s[le];
      float* mp = msg + (size_t)(pos - posLo)*2752;
      mp[lane]     = s0*mx[lane];
      mp[64+lane]  = (s10*W[0]+s11*W[1]+s12*W[2])*mx[64+lane];
      mp[128+lane] = (s20*W[3]+s21*W[4]+s22*W[5]+s23*W[6]+s24*W[7])*mx[128+lane];
      {
        float m = mx[192+lane]; int b = 192+3*lane;
        mp[b]=s10*m; mp[b+1]=s11*m; mp[b+2]=s12*m;
        m = mx[256+lane]; b = 192+(64+lane)*3;
        mp[b]=s0*sh[0]*m; mp[b+1]=s0*sh[1]*m; mp[b+2]=s0*sh[2]*m;
        m = mx[320+lane]; b = 192+(128+lane)*3;
        #pragma unroll
        for(int c=0;c<3;c++)
          mp[b+c] = (s10*W[8+c]+s11*W[11+c]+s12*W[14+c])*m;
        m = mx[384+lane]; b = 192+(192+lane)*3;
        #pragma unroll
        for(int c=0;c<3;c++)
          mp[b+c] = (s20*W[17+c]+s21*W[20+c]+s22*W[23+c]+s23*W[26+c]+s24*W[29+c])*m;
        m = mx[448+lane]; b = 192+(256+lane)*3;
        #pragma unroll
        for(int c=0;c<3;c++)
          mp[b+c] = (s20*W[32+c]+s21*W[35+c]+s22*W[38+c]+s23*W[41+c]+s24*W[44+c])*m;
      }
      {
        float m = mx[512+lane]; int b = 1152+5*lane;
        mp[b]=s20*m; mp[b+1]=s21*m; mp[b+2]=s22*m; mp[b+3]=s23*m; mp[b+4]=s24*m;
        m = mx[576+lane]; b = 1152+(64+lane)*5;
        #pragma unroll
        for(int c=0;c<5;c++) mp[b+c]=s0*sh[3+c]*m;
        m = mx[640+lane]; b = 1152+(128+lane)*5;
        #pragma unroll
        for(int c=0;c<5;c++)
          mp[b+c] = (s10*W[47+c]+s11*W[52+c]+s12*W[57+c])*m;
        m = mx[704+lane]; b = 1152+(192+lane)*5;
        #pragma unroll
        for(int c=0;c<5;c++)
          mp[b+c] = (s10*W[62+c]+s11*W[67+c]+s12*W[72+c])*m;
        m = mx[768+lane]; b = 1152+(256+lane)*5;
        #pragma unroll
        for(int c=0;c<5;c++)
          mp[b+c] = (s20*W[77+c]+s21*W[82+c]+s22*W[87+c]+s23*W[92+c]+s24*W[97+c])*m;
      }
    }
  }
}

// ---------------- Phase B: segment-sum of contiguous msg rows into a_packed ----------------
__global__ __launch_bounds__(256) void gather_kernel(
  const float* __restrict__ msg, const int* __restrict__ offsets,
  float* __restrict__ a_packed, int posLo, int posHi, int N)
{
  int n = blockIdx.x; if(n>=N) return;
  int e0 = offsets[n], e1 = offsets[n+1];
  if (e0 < posLo) e0 = posLo;
  if (e1 > posHi) e1 = posHi;
  if (e0 >= e1) return;
  float4* dst = (float4*)(a_packed + (size_t)n*2752);
  for (int i=threadIdx.x; i<688; i+=256){
    float4 a = dst[i];
    for (int p=e0; p<e1; p++){
      float4 v = ((const float4*)(msg + (size_t)(p-posLo)*2752))[i];
      a.x+=v.x; a.y+=v.y; a.z+=v.z; a.w+=v.w;
    }
    dst[i]=a;
  }
}

// ---------------- output GEMM: d = scaled GEMMs of a_packed, into dbuf (704/node) ----------------
// 11 segments: 0..2 d0 (cols 64s..64s+63, K=192); 3..5 d1 c=s-3 (K=320); 6..10 d2 c=s-6 (K=320)
__global__ __launch_bounds__(256) void out_gemm_kernel(
  const float* __restrict__ A, const float* __restrict__ Wd0,
  const float* __restrict__ Wd1, const float* __restrict__ Wd2,
  float* __restrict__ dbuf, int N)
{
  __shared__ float As[64][17];
  __shared__ float Bs[16][64];
  int tid = threadIdx.x;
  int tx = tid & 15, ty = tid >> 4;
  int s = blockIdx.y;
  int n0 = blockIdx.x*64;

  int abase, astride, K, obase, ostride, bcol0, bstride;
  const float* W;
  float scale;
  if (s < 3){
    abase = 0; astride = 1; K = 192; W = Wd0; bcol0 = 64*s; bstride = 192;
    obase = 64*s; ostride = 1;
    scale = 0.02282177322938192f;      // 1/sqrt(10*192)
  } else if (s < 6){
    int c = s-3;
    abase = 192+c; astride = 3; K = 320; W = Wd1; bcol0 = 0; bstride = 64;
    obase = 192+c; ostride = 3;
    scale = 0.017677669529663688f;     // 1/sqrt(10*320)
  } else {
    int c = s-6;
    abase = 1152+c; astride = 5; K = 320; W = Wd2; bcol0 = 0; bstride = 64;
    obase = 384+c; ostride = 5;
    scale = 0.017677669529663688f;
  }

  float acc[4][4];
  #pragma unroll
  for(int i=0;i<4;i++)
    #pragma unroll
    for(int j=0;j<4;j++) acc[i][j]=0.f;

  for (int k0=0; k0<K; k0+=16){
    #pragma unroll
    for (int l=0;l<4;l++){
      int idx = tid + l*256;
      int row = idx>>4, kk = idx&15;
      int n = n0+row;
      As[row][kk] = (n<N)? A[(size_t)n*2752 + abase + astride*(k0+kk)] : 0.f;
    }
    #pragma unroll
    for (int l=0;l<4;l++){
      int idx = tid + l*256;
      int kk = idx>>6, j = idx&63;
      Bs[kk][j] = W[(size_t)(k0+kk)*bstride + bcol0 + j];
    }
    __syncthreads();
    #pragma unroll
    for (int kk=0; kk<16; kk++){
      float av[4];
      #pragma unroll
      for(int i=0;i<4;i++) av[i] = As[ty*4+i][kk];
      float4 bv = *(const float4*)&Bs[kk][tx*4];
      #pragma unroll
      for(int i=0;i<4;i++){
        acc[i][0] += av[i]*bv.x; acc[i][1] += av[i]*bv.y;
        acc[i][2] += av[i]*bv.z; acc[i][3] += av[i]*bv.w;
      }
    }
    __syncthreads();
  }
  #pragma unroll
  for(int i=0;i<4;i++){
    int n = n0 + ty*4+i;
    if (n>=N) continue;
    #pragma unroll
    for(int j=0;j<4;j++){
      int col = tx*4+j;
      dbuf[(size_t)n*704 + obase + ostride*col] = acc[i][j]*scale;
    }
  }
}

// ---------------- epilogue: swish/gates + self connection ----------------
__global__ __launch_bounds__(256) void epilogue_kernel(
  const float* __restrict__ dbuf, const float* __restrict__ sc_packed,
  float* __restrict__ out, int N)
{
  int n = blockIdx.x; if(n>=N) return;
  const float* d = dbuf + (size_t)n*704;
  const float* sc = sc_packed + (size_t)n*576;
  float* o = out + (size_t)n*576;
  for (int p=threadIdx.x; p<576; p+=256){
    float v;
    if (p<64){
      float x = d[p];
      v = x/(1.f+expf(-x)) + sc[p];
    } else if (p<256){
      int r = p-64; int f = r/3;
      float g = d[64+f]; g = g/(1.f+expf(-g));
      v = d[192+r]*g + sc[p];
    } else {
      int r = p-256; int f = r/5;
      float g = d[128+f]; g = g/(1.f+expf(-g));
      v = d[384+r]*g + sc[p];
    }
    o[p] = v;
  }
}

// ---------------- host ----------------
extern "C" void kernel_launch(void* const* d_in, const int* in_sizes, int n_in,
                              void* d_out, int out_size, void* d_ws, size_t ws_size,
                              hipStream_t stream)
{
  const float* vectors    =(const float*)d_in[0];
  const float* node_feats =(const float*)d_in[1];
  const int*   node_specie=(const int*)  d_in[2];
  const int*   senders    =(const int*)  d_in[3];
  const int*   receivers  =(const int*)  d_in[4];
  const float* Wsc0=(const float*)d_in[5];
  const float* Wsc1=(const float*)d_in[6];
  const float* Wsc2=(const float*)d_in[7];
  const float* Wu0 =(const float*)d_in[8];
  const float* Wu1 =(const float*)d_in[9];
  const float* Wu2 =(const float*)d_in[10];
  const float* Wm1 =(const float*)d_in[11];
  const float* Wm2 =(const float*)d_in[12];
  const float* Wm3 =(const float*)d_in[13];
  const float* Wd0 =(const float*)d_in[14];
  const float* Wd1 =(const float*)d_in[15];
  const float* Wd2 =(const float*)d_in[16];
  float* out = (float*)d_out;

  int E = in_sizes[0]/3;
  int N = in_sizes[1]/576;
  int nspec = in_sizes[5]/4096;

  // workspace carve
  float* cgbuf     = (float*)d_ws;                         // 512
  float* g_packed  = cgbuf + 512;                          // N*576
  float* sc_packed = g_packed  + (size_t)N*576;            // N*576
  float* Wm3T      = sc_packed + (size_t)N*576;            // 832*64 = 53248
  float* a_packed  = Wm3T + 53248;                         // N*2752
  int*   counts    = (int*)(a_packed + (size_t)N*2752);    // N
  int*   offsets   = counts + N;                           // N+1
  int*   cursor    = offsets + (N+1);                      // N
  int*   edge_list = cursor + N;                           // E
  size_t used_bytes = (size_t)((char*)(edge_list + E) - (char*)d_ws);
  used_bytes = (used_bytes + 255) & ~(size_t)255;
  float* msg = (float*)((char*)d_ws + used_bytes);
  float* dbuf = msg;   // reuse msg region after all rounds (msg dead by then); needs N*704 floats
  size_t avail = (ws_size > used_bytes) ? (ws_size - used_bytes) : 0;
  long long cap = (long long)(avail / (2752u*4u));
  if (cap > E) cap = E;
  cap = (cap/EPB)*EPB;
  if (cap < EPB) cap = EPB;

  hipMemsetAsync(counts, 0, (size_t)N*sizeof(int), stream);
  hipMemsetAsync(a_packed, 0, (size_t)N*2752*sizeof(float), stream);
  cg_init_kernel<<<2,256,0,stream>>>(cgbuf);
  transpose_wm3_kernel<<<(64*832+255)/256,256,0,stream>>>(Wm3, Wm3T);
  if (nspec == 1){
    dim3 grid((N+63)/64, 18);
    node_gemm_kernel<<<grid,256,0,stream>>>(node_feats,Wsc0,Wsc1,Wsc2,Wu0,Wu1,Wu2,
                                            g_packed,sc_packed,N);
  } else {
    node_linear_kernel<<<N,256,0,stream>>>(node_feats,node_specie,Wsc0,Wsc1,Wsc2,Wu0,Wu1,Wu2,
                                           g_packed,sc_packed,N);
  }
  count_kernel<<<(E+255)/256,256,0,stream>>>(receivers,counts,E);
  scan_kernel<<<1,1024,0,stream>>>(counts,offsets,cursor,N);
  scatter_kernel<<<(E+255)/256,256,0,stream>>>(receivers,cursor,edge_list,E);

  for (long long lo=0; lo<E; lo+=cap){
    long long hi = lo + cap; if (hi > E) hi = E;
    int cnt = (int)(hi - lo);
    int blocks = (cnt + EPB - 1)/EPB;
    edge_msg_kernel<<<blocks,256,0,stream>>>(vectors,senders,edge_list,g_packed,
                                             Wm1,Wm2,Wm3T,cgbuf,msg,(int)lo,(int)hi);
    gather_kernel<<<N,256,0,stream>>>(msg,offsets,a_packed,(int)lo,(int)hi,N);
  }

  {
    dim3 grid((N+63)/64, 11);
    out_gemm_kernel<<<grid,256,0,stream>>>(a_packed,Wd0,Wd1,Wd2,dbuf,N);
  }
  epilogue_kernel<<<N,256,0,stream>>>(dbuf,sc_packed,out,N);
}

// Round 4
// 666.338 us; speedup vs baseline: 2.1440x; 1.0769x over previous
//
#include <hip/hip_runtime.h>
#include <math.h>

#define EPB 8           // edges per block in edge_lite kernel

// CG tensor offsets inside cg buffer (floats)
#define CG110 0
#define CG220 9
#define CG121 34
#define CG211 79
#define CG231 124
#define CG112 229
#define CG132 274
#define CG222 379
#define CGTOT 504

// ---------------- CG coefficient init (device, double precision) ----------------
__device__ double dfact(int n){ double r=1.0; for(int i=2;i<=n;i++) r*=(double)i; return r; }

__device__ double cg_coeff(int j1,int m1,int j2,int m2,int j3,int m3){
  if(m1+m2!=m3) return 0.0;
  int lo = j1>j2 ? j1-j2 : j2-j1;
  if(j3 < lo || j3 > j1+j2) return 0.0;
  double pref = sqrt((double)(2*j3+1)*dfact(j3+j1-j2)*dfact(j3-j1+j2)*dfact(j1+j2-j3)/dfact(j1+j2+j3+1));
  pref *= sqrt(dfact(j3+m3)*dfact(j3-m3)*dfact(j1-m1)*dfact(j1+m1)*dfact(j2-m2)*dfact(j2+m2));
  double s=0.0;
  for(int k=0;k<=j1+j2+j3;k++){
    int d0=j1+j2-j3-k, d1=j1-m1-k, d2=j2+m2-k, d3=j3-j2+m1+k, d4=j3-j1-m2+k;
    if(d0<0||d1<0||d2<0||d3<0||d4<0) continue;
    double term = 1.0/(dfact(k)*dfact(d0)*dfact(d1)*dfact(d2)*dfact(d3)*dfact(d4));
    s += (k&1)? -term : term;
  }
  return pref*s;
}

__device__ void u_elem(int l,int i,int a,double& re,double& im){
  const double s=0.70710678118654752440;
  re=0.0; im=0.0;
  int mi=i-l, ma=a-l;
  if(mi==0){ if(ma==0) re=1.0; }
  else if(mi>0){ if(ma==mi) re=(mi&1)?-s:s; else if(ma==-mi) re=s; }
  else { int m=-mi; if(ma==mi) im=s; else if(ma==-mi) im=(m&1)?s:-s; }
}

__device__ float real_cg_elem(int l1,int l2,int l3,int ii,int jj,int kk){
  double acc=0.0;
  int alist[2]={ii, 2*l1-ii}; int na=(alist[1]==alist[0])?1:2;
  int blist[2]={jj, 2*l2-jj}; int nb=(blist[1]==blist[0])?1:2;
  int clist[2]={kk, 2*l3-kk}; int nc=(clist[1]==clist[0])?1:2;
  for(int ai=0;ai<na;ai++) for(int bi=0;bi<nb;bi++) for(int ci=0;ci<nc;ci++){
    int a=alist[ai], b=blist[bi], c=clist[ci];
    double w = cg_coeff(l1,a-l1,l2,b-l2,l3,c-l3);
    if(w==0.0) continue;
    double u1r,u1i,u2r,u2i,u3r,u3i;
    u_elem(l1,ii,a,u1r,u1i); u_elem(l2,jj,b,u2r,u2i); u_elem(l3,kk,c,u3r,u3i);
    double ar = u1r*u2r - u1i*u2i;
    double aiv= u1r*u2i + u1i*u2r;
    acc += (ar*u3r + aiv*u3i)*w;
  }
  return (float)acc;
}

__global__ void cg_init_kernel(float* __restrict__ cgbuf){
  int tid = blockIdx.x*blockDim.x + threadIdx.x;
  if(tid>=CGTOT) return;
  const int l1s[8]={1,2,1,2,2,1,1,2};
  const int l2s[8]={1,2,2,1,3,1,3,2};
  const int l3s[8]={0,0,1,1,1,2,2,2};
  const int offs[9]={CG110,CG220,CG121,CG211,CG231,CG112,CG132,CG222,CGTOT};
  int t=0;
  for(int u=0;u<8;u++){ if(tid>=offs[u] && tid<offs[u+1]){ t=u; break; } }
  int l1=l1s[t], l2=l2s[t], l3=l3s[t];
  int rem = tid - offs[t];
  int d3=2*l3+1, d2=2*l2+1;
  int k = rem % d3; int j = (rem/d3)%d2; int i = rem/(d3*d2);
  cgbuf[tid] = real_cg_elem(l1,l2,l3,i,j,k);
}

// ---------------- node linears (fallback, species-dependent) ----------------
__global__ __launch_bounds__(256) void node_linear_kernel(
    const float* __restrict__ node_feats, const int* __restrict__ specie,
    const float* __restrict__ Wsc0, const float* __restrict__ Wsc1, const float* __restrict__ Wsc2,
    const float* __restrict__ Wu0,  const float* __restrict__ Wu1,  const float* __restrict__ Wu2,
    float* __restrict__ g_packed, float* __restrict__ sc_packed, int N)
{
  __shared__ float feat[576];
  int n = blockIdx.x; if(n>=N) return;
  const float4* src = (const float4*)(node_feats + (size_t)n*576);
  float4* fd = (float4*)feat;
  for(int i=threadIdx.x;i<144;i+=256) fd[i]=src[i];
  __syncthreads();
  int sp = specie[n];
  const float inv_f = 0.125f;
  for(int o=threadIdx.x; o<1152; o+=256){
    int isSc = (o>=576);
    int p = o - (isSc?576:0);
    float acc=0.f;
    if(p<64){
      const float* W = isSc ? (Wsc0 + (size_t)sp*4096) : Wu0;
      #pragma unroll 8
      for(int f=0; f<64; f++) acc += feat[f]*W[f*64+p];
    } else if(p<256){
      int q=p-64; int f=q/3, c=q-3*f;
      const float* W = isSc ? (Wsc1 + (size_t)sp*4096) : Wu1;
      #pragma unroll 8
      for(int fp=0; fp<64; fp++) acc += feat[64+3*fp+c]*W[fp*64+f];
    } else {
      int q=p-256; int f=q/5, c=q-5*f;
      const float* W = isSc ? (Wsc2 + (size_t)sp*4096) : Wu2;
      #pragma unroll 8
      for(int fp=0; fp<64; fp++) acc += feat[256+5*fp+c]*W[fp*64+f];
    }
    float* dst = isSc ? sc_packed : g_packed;
    dst[(size_t)n*576 + p] = acc*inv_f;
  }
}

// ---------------- node linears as tiled GEMM (n_species==1 fast path) ----------------
__global__ __launch_bounds__(256) void node_gemm_kernel(
  const float* __restrict__ node_feats,
  const float* __restrict__ Wsc0, const float* __restrict__ Wsc1, const float* __restrict__ Wsc2,
  const float* __restrict__ Wu0,  const float* __restrict__ Wu1,  const float* __restrict__ Wu2,
  float* __restrict__ g_packed, float* __restrict__ sc_packed, int N)
{
  __shared__ float As[64][17];
  __shared__ float Bs[16][64];
  int tid = threadIdx.x;
  int tx = tid & 15, ty = tid >> 4;
  int s = blockIdx.y;
  int n0 = blockIdx.x*64;

  int sub = s % 9;
  int isSc = (s >= 9);
  int abase, astride;
  const float* W;
  if (sub == 0){ abase = 0; astride = 1; W = isSc? Wsc0 : Wu0; }
  else if (sub < 4){ int c = sub-1; abase = 64+c; astride = 3; W = isSc? Wsc1 : Wu1; }
  else { int c = sub-4; abase = 256+c; astride = 5; W = isSc? Wsc2 : Wu2; }
  float* dst = isSc ? sc_packed : g_packed;

  float acc[4][4];
  #pragma unroll
  for(int i=0;i<4;i++)
    #pragma unroll
    for(int j=0;j<4;j++) acc[i][j]=0.f;

  for (int k0=0; k0<64; k0+=16){
    #pragma unroll
    for (int l=0;l<4;l++){
      int idx = tid + l*256;
      int row = idx>>4, kk = idx&15;
      int n = n0+row;
      As[row][kk] = (n<N)? node_feats[(size_t)n*576 + abase + astride*(k0+kk)] : 0.f;
    }
    #pragma unroll
    for (int l=0;l<4;l++){
      int idx = tid + l*256;
      int kk = idx>>6, j = idx&63;
      Bs[kk][j] = W[(k0+kk)*64 + j];
    }
    __syncthreads();
    #pragma unroll
    for (int kk=0; kk<16; kk++){
      float av[4];
      #pragma unroll
      for(int i=0;i<4;i++) av[i] = As[ty*4+i][kk];
      float4 bv = *(const float4*)&Bs[kk][tx*4];
      #pragma unroll
      for(int i=0;i<4;i++){
        acc[i][0] += av[i]*bv.x; acc[i][1] += av[i]*bv.y;
        acc[i][2] += av[i]*bv.z; acc[i][3] += av[i]*bv.w;
      }
    }
    __syncthreads();
  }
  const float scale = 0.125f;  // 1/sqrt(64)
  #pragma unroll
  for(int i=0;i<4;i++){
    int n = n0 + ty*4+i;
    if (n>=N) continue;
    #pragma unroll
    for(int j=0;j<4;j++){
      int f = tx*4+j;
      dst[(size_t)n*576 + abase + astride*f] = acc[i][j]*scale;
    }
  }
}

// ---------------- CSR build ----------------
__global__ void count_kernel(const int* __restrict__ recv, int* __restrict__ counts, int E){
  int e = blockIdx.x*256 + threadIdx.x;
  if(e<E) atomicAdd(&counts[recv[e]],1);
}

__global__ __launch_bounds__(1024) void scan_kernel(const int* __restrict__ counts,
                                                    int* __restrict__ offsets,
                                                    int* __restrict__ cursor, int n){
  __shared__ int tmp[1024];
  int tid = threadIdx.x;
  int per = (n + 1023)/1024;
  int base = tid*per;
  int s = 0;
  for(int i=0;i<per;i++){ int idx=base+i; if(idx<n) s += counts[idx]; }
  tmp[tid]=s; __syncthreads();
  for(int off=1; off<1024; off<<=1){
    int v = (tid>=off)? tmp[tid-off] : 0;
    __syncthreads();
    tmp[tid]+=v;
    __syncthreads();
  }
  int run = (tid==0)? 0 : tmp[tid-1];
  for(int i=0;i<per;i++){
    int idx=base+i;
    if(idx<n){ offsets[idx]=run; cursor[idx]=run; run += counts[idx]; }
  }
  if(tid==1023) offsets[n]=tmp[1023];
}

__global__ void scatter_kernel(const int* __restrict__ recv, int* __restrict__ cursor,
                               int* __restrict__ edge_list, int E){
  int e = blockIdx.x*256 + threadIdx.x;
  if(e<E){ int pos=atomicAdd(&cursor[recv[e]],1); edge_list[pos]=e; }
}

// ---------------- geometry per edge (pos-indexed): radial basis, sh, sender ----------------
__global__ __launch_bounds__(256) void geom_kernel(
  const float* __restrict__ vectors, const int* __restrict__ edge_list,
  const int* __restrict__ senders,
  float* __restrict__ radbuf, float* __restrict__ shbuf, int* __restrict__ spos, int E)
{
  int pos = blockIdx.x*256 + threadIdx.x;
  if (pos >= E) return;
  int e = edge_list[pos];
  spos[pos] = senders[e];
  float vx=vectors[e*3], vy=vectors[e*3+1], vz=vectors[e*3+2];
  float x2 = vx*vx+vy*vy+vz*vz;
  float x  = sqrtf(fmaxf(x2, 1e-12f));
  float inv= 1.f/x;
  float ux=vx*inv, uy=vy*inv, uz=vz*inv;
  float env = 0.f;
  if(x<1.f){
    float x3=x*x*x; float x6=x3*x3; float x7=x6*x; float x8=x7*x;
    env = 1.f-28.f*x6+48.f*x7-21.f*x8;
  }
  float* rb = radbuf + (size_t)pos*8;
  #pragma unroll
  for(int nn=1;nn<=8;nn++)
    rb[nn-1] = 1.4142135623730951f * sinf(3.14159265358979323846f*(float)nn*x)*inv*env;
  float sh[16];
  const float s3=1.7320508075688772f;
  sh[0]=s3*uy; sh[1]=s3*uz; sh[2]=s3*ux;
  const float s15=3.872983346207417f, s5=2.23606797749979f;
  sh[3]=s15*ux*uy; sh[4]=s15*uy*uz;
  sh[5]=0.5f*s5*(3.f*uz*uz-1.f);
  sh[6]=s15*ux*uz; sh[7]=0.5f*s15*(ux*ux-uy*uy);
  const float c35=2.091650066335189f, c105=10.246950765959598f;
  const float c21=1.620185174601965f, c7=1.3228756555322954f;
  sh[8] =c35*uy*(3.f*ux*ux-uy*uy);
  sh[9] =c105*ux*uy*uz;
  sh[10]=c21*uy*(5.f*uz*uz-1.f);
  sh[11]=c7*uz*(5.f*uz*uz-3.f);
  sh[12]=c21*ux*(5.f*uz*uz-1.f);
  sh[13]=0.5f*c105*uz*(ux*ux-uy*uy);
  sh[14]=c35*ux*(ux*ux-3.f*uy*uy);
  sh[15]=0.f;
  float* sb = shbuf + (size_t)pos*16;
  #pragma unroll
  for(int k=0;k<16;k++) sb[k]=sh[k];
}

// ---------------- per-edge TP weight tables (coalesced, task = (pos, idx<104)) ----------------
__global__ __launch_bounds__(256) void wtab_kernel(
  const float* __restrict__ shbuf, const float* __restrict__ cgbuf,
  float* __restrict__ wtabbuf, int E)
{
  __shared__ float cgs[504];
  for(int i=threadIdx.x;i<504;i+=256) cgs[i]=cgbuf[i];
  __syncthreads();
  long long t = (long long)blockIdx.x*256 + threadIdx.x;
  if (t >= (long long)E*104) return;
  int pos = (int)(t/104), idx = (int)(t - (long long)pos*104);
  const float* sh = shbuf + (size_t)pos*16;
  float v = 0.f;
  if (idx < 3){
    int i=idx;
    #pragma unroll
    for(int j=0;j<3;j++) v += sh[j]*cgs[CG110+i*3+j];
  } else if (idx < 8){
    int i=idx-3;
    #pragma unroll
    for(int j=0;j<5;j++) v += sh[3+j]*cgs[CG220+i*5+j];
  } else if (idx < 17){
    int r=idx-8; int i=r/3, c=r-3*i;
    #pragma unroll
    for(int j=0;j<5;j++) v += sh[3+j]*cgs[CG121+(i*5+j)*3+c];
  } else if (idx < 32){
    int r=idx-17; int i=r/3, c=r-3*i;
    #pragma unroll
    for(int j=0;j<3;j++) v += sh[j]*cgs[CG211+(i*3+j)*3+c];
  } else if (idx < 47){
    int r=idx-32; int i=r/3, c=r-3*i;
    #pragma unroll
    for(int j=0;j<7;j++) v += sh[8+j]*cgs[CG231+(i*7+j)*3+c];
  } else if (idx < 62){
    int r=idx-47; int i=r/5, c=r-5*i;
    #pragma unroll
    for(int j=0;j<3;j++) v += sh[j]*cgs[CG112+(i*3+j)*5+c];
  } else if (idx < 77){
    int r=idx-62; int i=r/5, c=r-5*i;
    #pragma unroll
    for(int j=0;j<7;j++) v += sh[8+j]*cgs[CG132+(i*7+j)*5+c];
  } else if (idx < 102){
    int r=idx-77; int i=r/5, c=r-5*i;
    #pragma unroll
    for(int j=0;j<5;j++) v += sh[3+j]*cgs[CG222+(i*5+j)*5+c];
  }
  wtabbuf[t] = v;
}

// ---------------- radial MLP: rad -> h1 -> h2 (4 edges/block) ----------------
__global__ __launch_bounds__(256) void h12_kernel(
  const float* __restrict__ radbuf, const float* __restrict__ Wm1,
  const float* __restrict__ Wm2, float* __restrict__ h2buf, int E)
{
  __shared__ float rloc[4][8];
  __shared__ float h1loc[4][64];
  int tid=threadIdx.x;
  int pos0 = blockIdx.x*4;
  if (tid<32){
    int le=tid>>3, i=tid&7;
    int p=pos0+le;
    rloc[le][i] = (p<E)? radbuf[(size_t)p*8+i] : 0.f;
  }
  __syncthreads();
  int le=tid>>6, j=tid&63;
  float a=0.f;
  #pragma unroll
  for(int i=0;i<8;i++) a += rloc[le][i]*Wm1[i*64+j];
  a *= 0.3535533905932738f;            // 1/sqrt(8)
  h1loc[le][j] = a/(1.f+expf(-a));
  __syncthreads();
  float b=0.f;
  #pragma unroll 16
  for(int i=0;i<64;i++) b += h1loc[le][i]*Wm2[i*64+j];
  b *= 0.125f;                          // 1/sqrt(64)
  int p=pos0+le;
  if (p<E) h2buf[(size_t)p*64+j] = b/(1.f+expf(-b));
}

// ---------------- mix = h2 @ Wm3 /8  (tiled GEMM per round) ----------------
__global__ __launch_bounds__(256) void mix_gemm_kernel(
  const float* __restrict__ h2buf, const float* __restrict__ Wm3,
  float* __restrict__ mixbuf, int posLo, int cnt)
{
  __shared__ float As[64][17];
  __shared__ float Bs[16][64];
  int tid=threadIdx.x; int tx=tid&15, ty=tid>>4;
  int r0 = blockIdx.x*64;
  int c0 = blockIdx.y*64;
  float acc[4][4];
  #pragma unroll
  for(int i=0;i<4;i++)
    #pragma unroll
    for(int j=0;j<4;j++) acc[i][j]=0.f;
  for(int k0=0;k0<64;k0+=16){
    #pragma unroll
    for(int l=0;l<4;l++){
      int idx=tid+l*256; int row=idx>>4, kk=idx&15;
      int r=r0+row;
      As[row][kk] = (r<cnt)? h2buf[(size_t)(posLo+r)*64 + k0+kk] : 0.f;
    }
    #pragma unroll
    for(int l=0;l<4;l++){
      int idx=tid+l*256; int kk=idx>>6, j=idx&63;
      Bs[kk][j] = Wm3[(size_t)(k0+kk)*832 + c0 + j];
    }
    __syncthreads();
    #pragma unroll
    for(int kk=0;kk<16;kk++){
      float av[4];
      #pragma unroll
      for(int i=0;i<4;i++) av[i]=As[ty*4+i][kk];
      float4 bv = *(const float4*)&Bs[kk][tx*4];
      #pragma unroll
      for(int i=0;i<4;i++){
        acc[i][0]+=av[i]*bv.x; acc[i][1]+=av[i]*bv.y;
        acc[i][2]+=av[i]*bv.z; acc[i][3]+=av[i]*bv.w;
      }
    }
    __syncthreads();
  }
  #pragma unroll
  for(int i=0;i<4;i++){
    int r=r0+ty*4+i;
    if(r>=cnt) continue;
    float4 o;
    o.x=acc[i][0]*0.125f; o.y=acc[i][1]*0.125f;
    o.z=acc[i][2]*0.125f; o.w=acc[i][3]*0.125f;
    *(float4*)&mixbuf[(size_t)r*832 + c0 + tx*4] = o;
  }
}

// ---------------- per-edge messages (component-major layout, coalesced writes) ----------------
// msg row (2752): [0,192) m0 ; [192,1152) m1 as c*320 + part*64 + f (c<3) ;
//                 [1152,2752) m2 as 1152 + c*320 + part*64 + f (c<5)
__global__ __launch_bounds__(256) void edge_lite_kernel(
  const float* __restrict__ g_packed, const int* __restrict__ spos,
  const float* __restrict__ shbuf, const float* __restrict__ wtabbuf,
  const float* __restrict__ mixbuf, float* __restrict__ msg,
  int posLo, int posHi)
{
  __shared__ float sh_s[EPB][16];
  __shared__ float wt_s[EPB][104];
  __shared__ int sidx[EPB];
  int tid=threadIdx.x;
  int base = posLo + blockIdx.x*EPB;
  int ecnt = min(EPB, posHi-base);
  if (ecnt<=0) return;
  if (tid<EPB){ int p = base + ((tid<ecnt)?tid:0); sidx[tid]=spos[p]; }
  for (int i=tid;i<EPB*16;i+=256){
    int le=i>>4, k=i&15; int p = base + ((le<ecnt)?le:0);
    sh_s[le][k]=shbuf[(size_t)p*16+k];
  }
  for (int i=tid;i<EPB*104;i+=256){
    int le=i/104, k=i-104*le; int p = base + ((le<ecnt)?le:0);
    wt_s[le][k]=wtabbuf[(size_t)p*104+k];
  }
  __syncthreads();
  int wave=tid>>6, lane=tid&63;
  for (int q=0;q<2;q++){
    int le=wave*2+q; if(le>=ecnt) continue;
    int rp = base+le-posLo;
    const float* g = g_packed + (size_t)sidx[le]*576;
    const float* mx = mixbuf + (size_t)rp*832;
    float* mp = msg + (size_t)rp*2752;
    const float* W  = wt_s[le];
    const float* sh = sh_s[le];
    float s0  = g[lane];
    float s10 = g[64+3*lane], s11 = g[65+3*lane], s12 = g[66+3*lane];
    float s20 = g[256+5*lane], s21 = g[257+5*lane], s22 = g[258+5*lane],
          s23 = g[259+5*lane], s24 = g[260+5*lane];
    // m0
    mp[lane]     = s0*mx[lane];
    mp[64+lane]  = (s10*W[0]+s11*W[1]+s12*W[2])*mx[64+lane];
    mp[128+lane] = (s20*W[3]+s21*W[4]+s22*W[5]+s23*W[6]+s24*W[7])*mx[128+lane];
    // m1 (comp-major)
    {
      float m0_=mx[192+lane], m1_=mx[256+lane], m2_=mx[320+lane],
            m3_=mx[384+lane], m4_=mx[448+lane];
      float p0[3]={s10,s11,s12};
      float v2[3], v3[3], v4[3];
      #pragma unroll
      for(int c=0;c<3;c++){
        v2[c] = s10*W[8+c]+s11*W[11+c]+s12*W[14+c];
        v3[c] = s20*W[17+c]+s21*W[20+c]+s22*W[23+c]+s23*W[26+c]+s24*W[29+c];
        v4[c] = s20*W[32+c]+s21*W[35+c]+s22*W[38+c]+s23*W[41+c]+s24*W[44+c];
      }
      #pragma unroll
      for(int c=0;c<3;c++){
        float* qp = mp + 192 + c*320;
        qp[lane]      = p0[c]*m0_;
        qp[64+lane]   = s0*sh[c]*m1_;
        qp[128+lane]  = v2[c]*m2_;
        qp[192+lane]  = v3[c]*m3_;
        qp[256+lane]  = v4[c]*m4_;
      }
    }
    // m2 (comp-major)
    {
      float m0_=mx[512+lane], m1_=mx[576+lane], m2_=mx[640+lane],
            m3_=mx[704+lane], m4_=mx[768+lane];
      float p0[5]={s20,s21,s22,s23,s24};
      float v2[5], v3[5], v4[5];
      #pragma unroll
      for(int c=0;c<5;c++){
        v2[c] = s10*W[47+c]+s11*W[52+c]+s12*W[57+c];
        v3[c] = s10*W[62+c]+s11*W[67+c]+s12*W[72+c];
        v4[c] = s20*W[77+c]+s21*W[82+c]+s22*W[87+c]+s23*W[92+c]+s24*W[97+c];
      }
      #pragma unroll
      for(int c=0;c<5;c++){
        float* qp = mp + 1152 + c*320;
        qp[lane]      = p0[c]*m0_;
        qp[64+lane]   = s0*sh[3+c]*m1_;
        qp[128+lane]  = v2[c]*m2_;
        qp[192+lane]  = v3[c]*m3_;
        qp[256+lane]  = v4[c]*m4_;
      }
    }
  }
}

// ---------------- segment-sum of contiguous msg rows ----------------
__global__ __launch_bounds__(256) void gather_kernel(
  const float* __restrict__ msg, const int* __restrict__ offsets,
  float* __restrict__ a_packed, int posLo, int posHi, int N)
{
  int n = blockIdx.x; if(n>=N) return;
  int i = blockIdx.y*256 + threadIdx.x;
  if (i>=688) return;
  int e0=offsets[n], e1=offsets[n+1];
  int a0 = e0>posLo? e0:posLo;
  int a1 = e1<posHi? e1:posHi;
  if (a0>=a1) return;
  float4* dst = (float4*)(a_packed + (size_t)n*2752);
  float4 a;
  if (a0==e0){ a.x=0.f;a.y=0.f;a.z=0.f;a.w=0.f; } else a = dst[i];
  for (int p=a0;p<a1;p++){
    float4 v = ((const float4*)(msg + (size_t)(p-posLo)*2752))[i];
    a.x+=v.x; a.y+=v.y; a.z+=v.z; a.w+=v.w;
  }
  dst[i]=a;
}

// ---------------- output GEMM into dbuf (704/node, comp-major d1/d2) ----------------
// 11 segments: s<3: d0 cols 64s.. (K=192); s in 3..5: d1 c=s-3 (K=320); s in 6..10: d2 c=s-6
__global__ __launch_bounds__(256) void out_gemm_kernel(
  const float* __restrict__ A, const float* __restrict__ Wd0,
  const float* __restrict__ Wd1, const float* __restrict__ Wd2,
  float* __restrict__ dbuf, int N)
{
  __shared__ float As[64][17];
  __shared__ float Bs[16][64];
  int tid = threadIdx.x;
  int tx = tid & 15, ty = tid >> 4;
  int s = blockIdx.y;
  int n0 = blockIdx.x*64;

  int abase, K, obase, bcol0, bstride;
  const float* W;
  float scale;
  if (s < 3){
    abase = 0; K = 192; W = Wd0; bcol0 = 64*s; bstride = 192;
    obase = 64*s;
    scale = 0.02282177322938192f;      // 1/sqrt(10*192)
  } else if (s < 6){
    int c = s-3;
    abase = 192+320*c; K = 320; W = Wd1; bcol0 = 0; bstride = 64;
    obase = 192+64*c;
    scale = 0.017677669529663688f;     // 1/sqrt(10*320)
  } else {
    int c = s-6;
    abase = 1152+320*c; K = 320; W = Wd2; bcol0 = 0; bstride = 64;
    obase = 384+64*c;
    scale = 0.017677669529663688f;
  }

  float acc[4][4];
  #pragma unroll
  for(int i=0;i<4;i++)
    #pragma unroll
    for(int j=0;j<4;j++) acc[i][j]=0.f;

  for (int k0=0; k0<K; k0+=16){
    #pragma unroll
    for (int l=0;l<4;l++){
      int idx = tid + l*256;
      int row = idx>>4, kk = idx&15;
      int n = n0+row;
      As[row][kk] = (n<N)? A[(size_t)n*2752 + abase + k0+kk] : 0.f;
    }
    #pragma unroll
    for (int l=0;l<4;l++){
      int idx = tid + l*256;
      int kk = idx>>6, j = idx&63;
      Bs[kk][j] = W[(size_t)(k0+kk)*bstride + bcol0 + j];
    }
    __syncthreads();
    #pragma unroll
    for (int kk=0; kk<16; kk++){
      float av[4];
      #pragma unroll
      for(int i=0;i<4;i++) av[i] = As[ty*4+i][kk];
      float4 bv = *(const float4*)&Bs[kk][tx*4];
      #pragma unroll
      for(int i=0;i<4;i++){
        acc[i][0] += av[i]*bv.x; acc[i][1] += av[i]*bv.y;
        acc[i][2] += av[i]*bv.z; acc[i][3] += av[i]*bv.w;
      }
    }
    __syncthreads();
  }
  #pragma unroll
  for(int i=0;i<4;i++){
    int n = n0 + ty*4+i;
    if (n>=N) continue;
    #pragma unroll
    for(int j=0;j<4;j++){
      int col = tx*4+j;
      dbuf[(size_t)n*704 + obase + col] = acc[i][j]*scale;
    }
  }
}

// ---------------- epilogue: swish/gates + self connection ----------------
__global__ __launch_bounds__(256) void epilogue_kernel(
  const float* __restrict__ dbuf, const float* __restrict__ sc_packed,
  float* __restrict__ out, int N)
{
  int n = blockIdx.x; if(n>=N) return;
  const float* d = dbuf + (size_t)n*704;
  const float* sc = sc_packed + (size_t)n*576;
  float* o = out + (size_t)n*576;
  for (int p=threadIdx.x; p<576; p+=256){
    float v;
    if (p<64){
      float x = d[p];
      v = x/(1.f+expf(-x)) + sc[p];
    } else if (p<256){
      int r = p-64; int f = r/3, c = r-3*f;
      float g = d[64+f]; g = g/(1.f+expf(-g));
      v = d[192+64*c+f]*g + sc[p];
    } else {
      int r = p-256; int f = r/5, c = r-5*f;
      float g = d[128+f]; g = g/(1.f+expf(-g));
      v = d[384+64*c+f]*g + sc[p];
    }
    o[p] = v;
  }
}

// ---------------- host ----------------
extern "C" void kernel_launch(void* const* d_in, const int* in_sizes, int n_in,
                              void* d_out, int out_size, void* d_ws, size_t ws_size,
                              hipStream_t stream)
{
  const float* vectors    =(const float*)d_in[0];
  const float* node_feats =(const float*)d_in[1];
  const int*   node_specie=(const int*)  d_in[2];
  const int*   senders    =(const int*)  d_in[3];
  const int*   receivers  =(const int*)  d_in[4];
  const float* Wsc0=(const float*)d_in[5];
  const float* Wsc1=(const float*)d_in[6];
  const float* Wsc2=(const float*)d_in[7];
  const float* Wu0 =(const float*)d_in[8];
  const float* Wu1 =(const float*)d_in[9];
  const float* Wu2 =(const float*)d_in[10];
  const float* Wm1 =(const float*)d_in[11];
  const float* Wm2 =(const float*)d_in[12];
  const float* Wm3 =(const float*)d_in[13];
  const float* Wd0 =(const float*)d_in[14];
  const float* Wd1 =(const float*)d_in[15];
  const float* Wd2 =(const float*)d_in[16];
  float* out = (float*)d_out;

  int E = in_sizes[0]/3;
  int N = in_sizes[1]/576;
  int nspec = in_sizes[5]/4096;

  // workspace carve
  float* cgbuf     = (float*)d_ws;                         // 512
  float* g_packed  = cgbuf + 512;                          // N*576
  float* sc_packed = g_packed  + (size_t)N*576;            // N*576
  float* a_packed  = sc_packed + (size_t)N*576;            // N*2752
  float* radbuf    = a_packed + (size_t)N*2752;            // E*8
  float* shbuf     = radbuf + (size_t)E*8;                 // E*16
  float* wtabbuf   = shbuf + (size_t)E*16;                 // E*104
  float* h2buf     = wtabbuf + (size_t)E*104;              // E*64
  int*   counts    = (int*)(h2buf + (size_t)E*64);         // N
  int*   offsets   = counts + N;                           // N+1
  int*   cursor    = offsets + (N+1);                      // N
  int*   edge_list = cursor + N;                           // E
  int*   spos      = edge_list + E;                        // E
  size_t used_bytes = (size_t)((char*)(spos + E) - (char*)d_ws);
  used_bytes = (used_bytes + 255) & ~(size_t)255;
  size_t avail = (ws_size > used_bytes) ? (ws_size - used_bytes) : 0;
  long long cap = (long long)(avail / ((832u+2752u)*4u));
  if (cap > 16384) cap = 16384;
  if (cap > E) cap = ((long long)E + 7) & ~7ll;
  cap = (cap/EPB)*EPB;
  if (cap < EPB) cap = EPB;
  float* mixbuf = (float*)((char*)d_ws + used_bytes);      // cap*832
  float* msg    = mixbuf + (size_t)cap*832;                // cap*2752
  float* dbuf   = mixbuf;                                  // reuse after rounds: N*704

  hipMemsetAsync(counts, 0, (size_t)N*sizeof(int), stream);
  hipMemsetAsync(a_packed, 0, (size_t)N*2752*sizeof(float), stream);
  cg_init_kernel<<<2,256,0,stream>>>(cgbuf);
  if (nspec == 1){
    dim3 grid((N+63)/64, 18);
    node_gemm_kernel<<<grid,256,0,stream>>>(node_feats,Wsc0,Wsc1,Wsc2,Wu0,Wu1,Wu2,
                                            g_packed,sc_packed,N);
  } else {
    node_linear_kernel<<<N,256,0,stream>>>(node_feats,node_specie,Wsc0,Wsc1,Wsc2,Wu0,Wu1,Wu2,
                                           g_packed,sc_packed,N);
  }
  count_kernel<<<(E+255)/256,256,0,stream>>>(receivers,counts,E);
  scan_kernel<<<1,1024,0,stream>>>(counts,offsets,cursor,N);
  scatter_kernel<<<(E+255)/256,256,0,stream>>>(receivers,cursor,edge_list,E);
  geom_kernel<<<(E+255)/256,256,0,stream>>>(vectors,edge_list,senders,radbuf,shbuf,spos,E);
  {
    long long tasks = (long long)E*104;
    wtab_kernel<<<(unsigned)((tasks+255)/256),256,0,stream>>>(shbuf,cgbuf,wtabbuf,E);
  }
  h12_kernel<<<(E+3)/4,256,0,stream>>>(radbuf,Wm1,Wm2,h2buf,E);

  for (long long lo=0; lo<E; lo+=cap){
    long long hi = lo + cap; if (hi > E) hi = E;
    int cnt = (int)(hi - lo);
    {
      dim3 grid((cnt+63)/64, 13);
      mix_gemm_kernel<<<grid,256,0,stream>>>(h2buf,Wm3,mixbuf,(int)lo,cnt);
    }
    edge_lite_kernel<<<(cnt+EPB-1)/EPB,256,0,stream>>>(g_packed,spos,shbuf,wtabbuf,
                                                       mixbuf,msg,(int)lo,(int)hi);
    {
      dim3 grid(N, 3);
      gather_kernel<<<grid,256,0,stream>>>(msg,offsets,a_packed,(int)lo,(int)hi,N);
    }
  }

  {
    dim3 grid((N+63)/64, 11);
    out_gemm_kernel<<<grid,256,0,stream>>>(a_packed,Wd0,Wd1,Wd2,dbuf,N);
  }
  epilogue_kernel<<<N,256,0,stream>>>(dbuf,sc_packed,out,N);
}

// Round 5
// 513.266 us; speedup vs baseline: 2.7834x; 1.2982x over previous
//
#include <hip/hip_runtime.h>
#include <math.h>

// CG tensor offsets inside cg buffer (floats)
#define CG110 0
#define CG220 9
#define CG121 34
#define CG211 79
#define CG231 124
#define CG112 229
#define CG132 274
#define CG222 379
#define CGTOT 504

// ---------------- CG coefficient init (device, double precision) ----------------
__device__ double dfact(int n){ double r=1.0; for(int i=2;i<=n;i++) r*=(double)i; return r; }

__device__ double cg_coeff(int j1,int m1,int j2,int m2,int j3,int m3){
  if(m1+m2!=m3) return 0.0;
  int lo = j1>j2 ? j1-j2 : j2-j1;
  if(j3 < lo || j3 > j1+j2) return 0.0;
  double pref = sqrt((double)(2*j3+1)*dfact(j3+j1-j2)*dfact(j3-j1+j2)*dfact(j1+j2-j3)/dfact(j1+j2+j3+1));
  pref *= sqrt(dfact(j3+m3)*dfact(j3-m3)*dfact(j1-m1)*dfact(j1+m1)*dfact(j2-m2)*dfact(j2+m2));
  double s=0.0;
  for(int k=0;k<=j1+j2+j3;k++){
    int d0=j1+j2-j3-k, d1=j1-m1-k, d2=j2+m2-k, d3=j3-j2+m1+k, d4=j3-j1-m2+k;
    if(d0<0||d1<0||d2<0||d3<0||d4<0) continue;
    double term = 1.0/(dfact(k)*dfact(d0)*dfact(d1)*dfact(d2)*dfact(d3)*dfact(d4));
    s += (k&1)? -term : term;
  }
  return pref*s;
}

__device__ void u_elem(int l,int i,int a,double& re,double& im){
  const double s=0.70710678118654752440;
  re=0.0; im=0.0;
  int mi=i-l, ma=a-l;
  if(mi==0){ if(ma==0) re=1.0; }
  else if(mi>0){ if(ma==mi) re=(mi&1)?-s:s; else if(ma==-mi) re=s; }
  else { int m=-mi; if(ma==mi) im=s; else if(ma==-mi) im=(m&1)?s:-s; }
}

__device__ float real_cg_elem(int l1,int l2,int l3,int ii,int jj,int kk){
  double acc=0.0;
  int alist[2]={ii, 2*l1-ii}; int na=(alist[1]==alist[0])?1:2;
  int blist[2]={jj, 2*l2-jj}; int nb=(blist[1]==blist[0])?1:2;
  int clist[2]={kk, 2*l3-kk}; int nc=(clist[1]==clist[0])?1:2;
  for(int ai=0;ai<na;ai++) for(int bi=0;bi<nb;bi++) for(int ci=0;ci<nc;ci++){
    int a=alist[ai], b=blist[bi], c=clist[ci];
    double w = cg_coeff(l1,a-l1,l2,b-l2,l3,c-l3);
    if(w==0.0) continue;
    double u1r,u1i,u2r,u2i,u3r,u3i;
    u_elem(l1,ii,a,u1r,u1i); u_elem(l2,jj,b,u2r,u2i); u_elem(l3,kk,c,u3r,u3i);
    double ar = u1r*u2r - u1i*u2i;
    double aiv= u1r*u2i + u1i*u2r;
    acc += (ar*u3r + aiv*u3i)*w;
  }
  return (float)acc;
}

__global__ void cg_init_kernel(float* __restrict__ cgbuf){
  int tid = blockIdx.x*blockDim.x + threadIdx.x;
  if(tid>=CGTOT) return;
  const int l1s[8]={1,2,1,2,2,1,1,2};
  const int l2s[8]={1,2,2,1,3,1,3,2};
  const int l3s[8]={0,0,1,1,1,2,2,2};
  const int offs[9]={CG110,CG220,CG121,CG211,CG231,CG112,CG132,CG222,CGTOT};
  int t=0;
  for(int u=0;u<8;u++){ if(tid>=offs[u] && tid<offs[u+1]){ t=u; break; } }
  int l1=l1s[t], l2=l2s[t], l3=l3s[t];
  int rem = tid - offs[t];
  int d3=2*l3+1, d2=2*l2+1;
  int k = rem % d3; int j = (rem/d3)%d2; int i = rem/(d3*d2);
  cgbuf[tid] = real_cg_elem(l1,l2,l3,i,j,k);
}

// g_packed layout (per node, 576): [0,64) l0 f ; [64,256) l1 c*64+f ; [256,576) l2 c*64+f
// sc_packed layout: reference-interleaved (f,c) to match output.

// ---------------- node linears (fallback, species-dependent) ----------------
__global__ __launch_bounds__(256) void node_linear_kernel(
    const float* __restrict__ node_feats, const int* __restrict__ specie,
    const float* __restrict__ Wsc0, const float* __restrict__ Wsc1, const float* __restrict__ Wsc2,
    const float* __restrict__ Wu0,  const float* __restrict__ Wu1,  const float* __restrict__ Wu2,
    float* __restrict__ g_packed, float* __restrict__ sc_packed, int N)
{
  __shared__ float feat[576];
  int n = blockIdx.x; if(n>=N) return;
  const float4* src = (const float4*)(node_feats + (size_t)n*576);
  float4* fd = (float4*)feat;
  for(int i=threadIdx.x;i<144;i+=256) fd[i]=src[i];
  __syncthreads();
  int sp = specie[n];
  const float inv_f = 0.125f;
  for(int o=threadIdx.x; o<1152; o+=256){
    int isSc = (o>=576);
    int p = o - (isSc?576:0);
    float acc=0.f;
    if(p<64){
      const float* W = isSc ? (Wsc0 + (size_t)sp*4096) : Wu0;
      #pragma unroll 8
      for(int f=0; f<64; f++) acc += feat[f]*W[f*64+p];
    } else if(p<256){
      int q=p-64; int f,c;
      if (isSc){ f=q/3; c=q-3*f; } else { c=q>>6; f=q&63; }
      const float* W = isSc ? (Wsc1 + (size_t)sp*4096) : Wu1;
      #pragma unroll 8
      for(int fp=0; fp<64; fp++) acc += feat[64+3*fp+c]*W[fp*64+f];
    } else {
      int q=p-256; int f,c;
      if (isSc){ f=q/5; c=q-5*f; } else { c=q>>6; f=q&63; }
      const float* W = isSc ? (Wsc2 + (size_t)sp*4096) : Wu2;
      #pragma unroll 8
      for(int fp=0; fp<64; fp++) acc += feat[256+5*fp+c]*W[fp*64+f];
    }
    float* dst = isSc ? sc_packed : g_packed;
    dst[(size_t)n*576 + p] = acc*inv_f;
  }
}

// ---------------- node linears as tiled GEMM (n_species==1 fast path) ----------------
__global__ __launch_bounds__(256) void node_gemm_kernel(
  const float* __restrict__ node_feats,
  const float* __restrict__ Wsc0, const float* __restrict__ Wsc1, const float* __restrict__ Wsc2,
  const float* __restrict__ Wu0,  const float* __restrict__ Wu1,  const float* __restrict__ Wu2,
  float* __restrict__ g_packed, float* __restrict__ sc_packed, int N)
{
  __shared__ float As[64][17];
  __shared__ float Bs[16][64];
  int tid = threadIdx.x;
  int tx = tid & 15, ty = tid >> 4;
  int s = blockIdx.y;
  int n0 = blockIdx.x*64;

  int sub = s % 9;
  int isSc = (s >= 9);
  int abase, astride;
  const float* W;
  if (sub == 0){ abase = 0; astride = 1; W = isSc? Wsc0 : Wu0; }
  else if (sub < 4){ int c = sub-1; abase = 64+c; astride = 3; W = isSc? Wsc1 : Wu1; }
  else { int c = sub-4; abase = 256+c; astride = 5; W = isSc? Wsc2 : Wu2; }
  // output placement
  int obase, ostride;
  if (isSc){ obase = abase; ostride = astride; }
  else {
    if (sub==0){ obase=0; ostride=1; }
    else if (sub<4){ obase = 64+64*(sub-1); ostride=1; }
    else { obase = 256+64*(sub-4); ostride=1; }
  }
  float* dst = isSc ? sc_packed : g_packed;

  float acc[4][4];
  #pragma unroll
  for(int i=0;i<4;i++)
    #pragma unroll
    for(int j=0;j<4;j++) acc[i][j]=0.f;

  for (int k0=0; k0<64; k0+=16){
    #pragma unroll
    for (int l=0;l<4;l++){
      int idx = tid + l*256;
      int row = idx>>4, kk = idx&15;
      int n = n0+row;
      As[row][kk] = (n<N)? node_feats[(size_t)n*576 + abase + astride*(k0+kk)] : 0.f;
    }
    #pragma unroll
    for (int l=0;l<4;l++){
      int idx = tid + l*256;
      int kk = idx>>6, j = idx&63;
      Bs[kk][j] = W[(k0+kk)*64 + j];
    }
    __syncthreads();
    #pragma unroll
    for (int kk=0; kk<16; kk++){
      float av[4];
      #pragma unroll
      for(int i=0;i<4;i++) av[i] = As[ty*4+i][kk];
      float4 bv = *(const float4*)&Bs[kk][tx*4];
      #pragma unroll
      for(int i=0;i<4;i++){
        acc[i][0] += av[i]*bv.x; acc[i][1] += av[i]*bv.y;
        acc[i][2] += av[i]*bv.z; acc[i][3] += av[i]*bv.w;
      }
    }
    __syncthreads();
  }
  const float scale = 0.125f;  // 1/sqrt(64)
  #pragma unroll
  for(int i=0;i<4;i++){
    int n = n0 + ty*4+i;
    if (n>=N) continue;
    #pragma unroll
    for(int j=0;j<4;j++){
      int f = tx*4+j;
      dst[(size_t)n*576 + obase + ostride*f] = acc[i][j]*scale;
    }
  }
}

// ---------------- CSR build ----------------
__global__ void count_kernel(const int* __restrict__ recv, int* __restrict__ counts, int E){
  int e = blockIdx.x*256 + threadIdx.x;
  if(e<E) atomicAdd(&counts[recv[e]],1);
}

__global__ __launch_bounds__(1024) void scan_kernel(const int* __restrict__ counts,
                                                    int* __restrict__ offsets,
                                                    int* __restrict__ cursor, int n){
  __shared__ int tmp[1024];
  int tid = threadIdx.x;
  int per = (n + 1023)/1024;
  int base = tid*per;
  int s = 0;
  for(int i=0;i<per;i++){ int idx=base+i; if(idx<n) s += counts[idx]; }
  tmp[tid]=s; __syncthreads();
  for(int off=1; off<1024; off<<=1){
    int v = (tid>=off)? tmp[tid-off] : 0;
    __syncthreads();
    tmp[tid]+=v;
    __syncthreads();
  }
  int run = (tid==0)? 0 : tmp[tid-1];
  for(int i=0;i<per;i++){
    int idx=base+i;
    if(idx<n){ offsets[idx]=run; cursor[idx]=run; run += counts[idx]; }
  }
  if(tid==1023) offsets[n]=tmp[1023];
}

__global__ void scatter_kernel(const int* __restrict__ recv, int* __restrict__ cursor,
                               int* __restrict__ edge_list, int E){
  int e = blockIdx.x*256 + threadIdx.x;
  if(e<E){ int pos=atomicAdd(&cursor[recv[e]],1); edge_list[pos]=e; }
}

// ---------------- geometry per edge (pos-indexed) ----------------
__global__ __launch_bounds__(256) void geom_kernel(
  const float* __restrict__ vectors, const int* __restrict__ edge_list,
  const int* __restrict__ senders,
  float* __restrict__ radbuf, float* __restrict__ shbuf, int* __restrict__ spos, int E)
{
  int pos = blockIdx.x*256 + threadIdx.x;
  if (pos >= E) return;
  int e = edge_list[pos];
  spos[pos] = senders[e];
  float vx=vectors[e*3], vy=vectors[e*3+1], vz=vectors[e*3+2];
  float x2 = vx*vx+vy*vy+vz*vz;
  float x  = sqrtf(fmaxf(x2, 1e-12f));
  float inv= 1.f/x;
  float ux=vx*inv, uy=vy*inv, uz=vz*inv;
  float env = 0.f;
  if(x<1.f){
    float x3=x*x*x; float x6=x3*x3; float x7=x6*x; float x8=x7*x;
    env = 1.f-28.f*x6+48.f*x7-21.f*x8;
  }
  float* rb = radbuf + (size_t)pos*8;
  #pragma unroll
  for(int nn=1;nn<=8;nn++)
    rb[nn-1] = 1.4142135623730951f * sinf(3.14159265358979323846f*(float)nn*x)*inv*env;
  float sh[16];
  const float s3=1.7320508075688772f;
  sh[0]=s3*uy; sh[1]=s3*uz; sh[2]=s3*ux;
  const float s15=3.872983346207417f, s5=2.23606797749979f;
  sh[3]=s15*ux*uy; sh[4]=s15*uy*uz;
  sh[5]=0.5f*s5*(3.f*uz*uz-1.f);
  sh[6]=s15*ux*uz; sh[7]=0.5f*s15*(ux*ux-uy*uy);
  const float c35=2.091650066335189f, c105=10.246950765959598f;
  const float c21=1.620185174601965f, c7=1.3228756555322954f;
  sh[8] =c35*uy*(3.f*ux*ux-uy*uy);
  sh[9] =c105*ux*uy*uz;
  sh[10]=c21*uy*(5.f*uz*uz-1.f);
  sh[11]=c7*uz*(5.f*uz*uz-3.f);
  sh[12]=c21*ux*(5.f*uz*uz-1.f);
  sh[13]=0.5f*c105*uz*(ux*ux-uy*uy);
  sh[14]=c35*ux*(ux*ux-3.f*uy*uy);
  sh[15]=0.f;
  float* sb = shbuf + (size_t)pos*16;
  #pragma unroll
  for(int k=0;k<16;k++) sb[k]=sh[k];
}

// ---------------- per-edge TP weight tables ----------------
__global__ __launch_bounds__(256) void wtab_kernel(
  const float* __restrict__ shbuf, const float* __restrict__ cgbuf,
  float* __restrict__ wtabbuf, int E)
{
  __shared__ float cgs[504];
  for(int i=threadIdx.x;i<504;i+=256) cgs[i]=cgbuf[i];
  __syncthreads();
  long long t = (long long)blockIdx.x*256 + threadIdx.x;
  if (t >= (long long)E*104) return;
  int pos = (int)(t/104), idx = (int)(t - (long long)pos*104);
  const float* sh = shbuf + (size_t)pos*16;
  float v = 0.f;
  if (idx < 3){
    int i=idx;
    #pragma unroll
    for(int j=0;j<3;j++) v += sh[j]*cgs[CG110+i*3+j];
  } else if (idx < 8){
    int i=idx-3;
    #pragma unroll
    for(int j=0;j<5;j++) v += sh[3+j]*cgs[CG220+i*5+j];
  } else if (idx < 17){
    int r=idx-8; int i=r/3, c=r-3*i;
    #pragma unroll
    for(int j=0;j<5;j++) v += sh[3+j]*cgs[CG121+(i*5+j)*3+c];
  } else if (idx < 32){
    int r=idx-17; int i=r/3, c=r-3*i;
    #pragma unroll
    for(int j=0;j<3;j++) v += sh[j]*cgs[CG211+(i*3+j)*3+c];
  } else if (idx < 47){
    int r=idx-32; int i=r/3, c=r-3*i;
    #pragma unroll
    for(int j=0;j<7;j++) v += sh[8+j]*cgs[CG231+(i*7+j)*3+c];
  } else if (idx < 62){
    int r=idx-47; int i=r/5, c=r-5*i;
    #pragma unroll
    for(int j=0;j<3;j++) v += sh[j]*cgs[CG112+(i*3+j)*5+c];
  } else if (idx < 77){
    int r=idx-62; int i=r/5, c=r-5*i;
    #pragma unroll
    for(int j=0;j<7;j++) v += sh[8+j]*cgs[CG132+(i*7+j)*5+c];
  } else if (idx < 102){
    int r=idx-77; int i=r/5, c=r-5*i;
    #pragma unroll
    for(int j=0;j<5;j++) v += sh[3+j]*cgs[CG222+(i*5+j)*5+c];
  }
  wtabbuf[t] = v;
}

// ---------------- radial MLP: rad -> h1 -> h2 (4 edges/block) ----------------
__global__ __launch_bounds__(256) void h12_kernel(
  const float* __restrict__ radbuf, const float* __restrict__ Wm1,
  const float* __restrict__ Wm2, float* __restrict__ h2buf, int E)
{
  __shared__ float rloc[4][8];
  __shared__ float h1loc[4][64];
  int tid=threadIdx.x;
  int pos0 = blockIdx.x*4;
  if (tid<32){
    int le=tid>>3, i=tid&7;
    int p=pos0+le;
    rloc[le][i] = (p<E)? radbuf[(size_t)p*8+i] : 0.f;
  }
  __syncthreads();
  int le=tid>>6, j=tid&63;
  float a=0.f;
  #pragma unroll
  for(int i=0;i<8;i++) a += rloc[le][i]*Wm1[i*64+j];
  a *= 0.3535533905932738f;            // 1/sqrt(8)
  h1loc[le][j] = a/(1.f+expf(-a));
  __syncthreads();
  float b=0.f;
  #pragma unroll 16
  for(int i=0;i<64;i++) b += h1loc[le][i]*Wm2[i*64+j];
  b *= 0.125f;                          // 1/sqrt(64)
  int p=pos0+le;
  if (p<E) h2buf[(size_t)p*64+j] = b/(1.f+expf(-b));
}

// ---------------- mix = h2 @ Wm3 /8  (tiled GEMM per round) ----------------
__global__ __launch_bounds__(256) void mix_gemm_kernel(
  const float* __restrict__ h2buf, const float* __restrict__ Wm3,
  float* __restrict__ mixbuf, int posLo, int cnt)
{
  __shared__ float As[64][17];
  __shared__ float Bs[16][64];
  int tid=threadIdx.x; int tx=tid&15, ty=tid>>4;
  int r0 = blockIdx.x*64;
  int c0 = blockIdx.y*64;
  float acc[4][4];
  #pragma unroll
  for(int i=0;i<4;i++)
    #pragma unroll
    for(int j=0;j<4;j++) acc[i][j]=0.f;
  for(int k0=0;k0<64;k0+=16){
    #pragma unroll
    for(int l=0;l<4;l++){
      int idx=tid+l*256; int row=idx>>4, kk=idx&15;
      int r=r0+row;
      As[row][kk] = (r<cnt)? h2buf[(size_t)(posLo+r)*64 + k0+kk] : 0.f;
    }
    #pragma unroll
    for(int l=0;l<4;l++){
      int idx=tid+l*256; int kk=idx>>6, j=idx&63;
      Bs[kk][j] = Wm3[(size_t)(k0+kk)*832 + c0 + j];
    }
    __syncthreads();
    #pragma unroll
    for(int kk=0;kk<16;kk++){
      float av[4];
      #pragma unroll
      for(int i=0;i<4;i++) av[i]=As[ty*4+i][kk];
      float4 bv = *(const float4*)&Bs[kk][tx*4];
      #pragma unroll
      for(int i=0;i<4;i++){
        acc[i][0]+=av[i]*bv.x; acc[i][1]+=av[i]*bv.y;
        acc[i][2]+=av[i]*bv.z; acc[i][3]+=av[i]*bv.w;
      }
    }
    __syncthreads();
  }
  #pragma unroll
  for(int i=0;i<4;i++){
    int r=r0+ty*4+i;
    if(r>=cnt) continue;
    float4 o;
    o.x=acc[i][0]*0.125f; o.y=acc[i][1]*0.125f;
    o.z=acc[i][2]*0.125f; o.w=acc[i][3]*0.125f;
    *(float4*)&mixbuf[(size_t)r*832 + c0 + tx*4] = o;
  }
}

// ---------------- fused message + segment-sum: one block per node, acc in registers ----------------
// a_packed row (2752): [0,192) m0 ; [192,1152) m1 c*320+part*64+f ; [1152,2752) m2 c*320+part*64+f
__global__ __launch_bounds__(256) void node_accum_kernel(
  const float* __restrict__ g_packed, const int* __restrict__ spos,
  const float* __restrict__ shbuf, const float* __restrict__ wtabbuf,
  const float* __restrict__ mixbuf, const int* __restrict__ offsets,
  float* __restrict__ a_packed, int posLo, int posHi, int N)
{
  __shared__ float accs[2752];
  __shared__ float wt_l[4][112];
  int n = blockIdx.x; if (n>=N) return;
  int tid = threadIdx.x, wave = tid>>6, lane = tid&63;
  int e0 = offsets[n], e1 = offsets[n+1];
  int a0 = e0>posLo? e0:posLo;
  int a1 = e1<posHi? e1:posHi;
  bool first = (posLo==0);
  if (!first && a0>=a1) return;

  for (int i=tid;i<2752;i+=256) accs[i]=0.f;

  float racc[43];
  #pragma unroll
  for(int k=0;k<43;k++) racc[k]=0.f;

  for (int pos=a0+wave; pos<a1; pos+=4){
    int rp = pos - posLo;
    // stage wtab (104) + sh[0..7] into wave-local LDS (in-order LDS within wave, no barrier)
    const float* wsrc = wtabbuf + (size_t)pos*104;
    wt_l[wave][lane] = wsrc[lane];
    if (lane<40) wt_l[wave][64+lane] = wsrc[64+lane];
    else if (lane<48) wt_l[wave][64+lane] = shbuf[(size_t)pos*16 + (lane-40)];
    const float* g = g_packed + (size_t)spos[pos]*576;
    const float* mx = mixbuf + (size_t)rp*832;
    float s0  = g[lane];
    float s10 = g[64+lane],  s11 = g[128+lane], s12 = g[192+lane];
    float s20 = g[256+lane], s21 = g[320+lane], s22 = g[384+lane],
          s23 = g[448+lane], s24 = g[512+lane];
    const float* W = wt_l[wave];
    const float* shv = W + 104;           // sh[0..7]
    // m0
    racc[0] += s0*mx[lane];
    racc[1] += (s10*W[0]+s11*W[1]+s12*W[2])*mx[64+lane];
    racc[2] += (s20*W[3]+s21*W[4]+s22*W[5]+s23*W[6]+s24*W[7])*mx[128+lane];
    // m1
    {
      float m0_=mx[192+lane], m1_=mx[256+lane], m2_=mx[320+lane],
            m3_=mx[384+lane], m4_=mx[448+lane];
      float p1v[3]={s10,s11,s12};
      #pragma unroll
      for(int c=0;c<3;c++){
        float v2 = s10*W[8+c]+s11*W[11+c]+s12*W[14+c];
        float v3 = s20*W[17+c]+s21*W[20+c]+s22*W[23+c]+s23*W[26+c]+s24*W[29+c];
        float v4 = s20*W[32+c]+s21*W[35+c]+s22*W[38+c]+s23*W[41+c]+s24*W[44+c];
        racc[3+c*5+0] += p1v[c]*m0_;
        racc[3+c*5+1] += s0*shv[c]*m1_;
        racc[3+c*5+2] += v2*m2_;
        racc[3+c*5+3] += v3*m3_;
        racc[3+c*5+4] += v4*m4_;
      }
    }
    // m2
    {
      float n0_=mx[512+lane], n1_=mx[576+lane], n2_=mx[640+lane],
            n3_=mx[704+lane], n4_=mx[768+lane];
      float p2v[5]={s20,s21,s22,s23,s24};
      #pragma unroll
      for(int c=0;c<5;c++){
        float v2 = s10*W[47+c]+s11*W[52+c]+s12*W[57+c];
        float v3 = s10*W[62+c]+s11*W[67+c]+s12*W[72+c];
        float v4 = s20*W[77+c]+s21*W[82+c]+s22*W[87+c]+s23*W[92+c]+s24*W[97+c];
        racc[18+c*5+0] += p2v[c]*n0_;
        racc[18+c*5+1] += s0*shv[3+c]*n1_;
        racc[18+c*5+2] += v2*n2_;
        racc[18+c*5+3] += v3*n3_;
        racc[18+c*5+4] += v4*n4_;
      }
    }
  }
  __syncthreads();
  // cross-wave merge (4 phases)
  for (int w=0; w<4; w++){
    if (wave==w){
      accs[lane]     += racc[0];
      accs[64+lane]  += racc[1];
      accs[128+lane] += racc[2];
      #pragma unroll
      for(int c=0;c<3;c++)
        #pragma unroll
        for(int p=0;p<5;p++)
          accs[192+c*320+p*64+lane] += racc[3+c*5+p];
      #pragma unroll
      for(int c=0;c<5;c++)
        #pragma unroll
        for(int p=0;p<5;p++)
          accs[1152+c*320+p*64+lane] += racc[18+c*5+p];
    }
    __syncthreads();
  }
  if (first){
    for (int i=tid;i<2752;i+=256) a_packed[(size_t)n*2752+i] = accs[i];
  } else {
    for (int i=tid;i<2752;i+=256) a_packed[(size_t)n*2752+i] += accs[i];
  }
}

// ---------------- output GEMM into dbuf (704/node, comp-major d1/d2), 32-row tiles ----------------
__global__ __launch_bounds__(256) void out_gemm_kernel(
  const float* __restrict__ A, const float* __restrict__ Wd0,
  const float* __restrict__ Wd1, const float* __restrict__ Wd2,
  float* __restrict__ dbuf, int N)
{
  __shared__ float As[32][17];
  __shared__ float Bs[16][64];
  int tid = threadIdx.x;
  int tx = tid & 15, ty = tid >> 4;
  int s = blockIdx.y;
  int n0 = blockIdx.x*32;

  int abase, K, obase, bcol0, bstride;
  const float* W;
  float scale;
  if (s < 3){
    abase = 0; K = 192; W = Wd0; bcol0 = 64*s; bstride = 192;
    obase = 64*s;
    scale = 0.02282177322938192f;      // 1/sqrt(10*192)
  } else if (s < 6){
    int c = s-3;
    abase = 192+320*c; K = 320; W = Wd1; bcol0 = 0; bstride = 64;
    obase = 192+64*c;
    scale = 0.017677669529663688f;     // 1/sqrt(10*320)
  } else {
    int c = s-6;
    abase = 1152+320*c; K = 320; W = Wd2; bcol0 = 0; bstride = 64;
    obase = 384+64*c;
    scale = 0.017677669529663688f;
  }

  float acc[2][4];
  #pragma unroll
  for(int i=0;i<2;i++)
    #pragma unroll
    for(int j=0;j<4;j++) acc[i][j]=0.f;

  for (int k0=0; k0<K; k0+=16){
    #pragma unroll
    for (int l=0;l<2;l++){
      int idx = tid + l*256;
      int row = idx>>4, kk = idx&15;
      int n = n0+row;
      As[row][kk] = (n<N)? A[(size_t)n*2752 + abase + k0+kk] : 0.f;
    }
    #pragma unroll
    for (int l=0;l<4;l++){
      int idx = tid + l*256;
      int kk = idx>>6, j = idx&63;
      Bs[kk][j] = W[(size_t)(k0+kk)*bstride + bcol0 + j];
    }
    __syncthreads();
    #pragma unroll
    for (int kk=0; kk<16; kk++){
      float av[2];
      av[0] = As[ty*2][kk]; av[1] = As[ty*2+1][kk];
      float4 bv = *(const float4*)&Bs[kk][tx*4];
      #pragma unroll
      for(int i=0;i<2;i++){
        acc[i][0] += av[i]*bv.x; acc[i][1] += av[i]*bv.y;
        acc[i][2] += av[i]*bv.z; acc[i][3] += av[i]*bv.w;
      }
    }
    __syncthreads();
  }
  #pragma unroll
  for(int i=0;i<2;i++){
    int n = n0 + ty*2+i;
    if (n>=N) continue;
    #pragma unroll
    for(int j=0;j<4;j++){
      int col = tx*4+j;
      dbuf[(size_t)n*704 + obase + col] = acc[i][j]*scale;
    }
  }
}

// ---------------- epilogue: swish/gates + self connection ----------------
__global__ __launch_bounds__(256) void epilogue_kernel(
  const float* __restrict__ dbuf, const float* __restrict__ sc_packed,
  float* __restrict__ out, int N)
{
  int n = blockIdx.x; if(n>=N) return;
  const float* d = dbuf + (size_t)n*704;
  const float* sc = sc_packed + (size_t)n*576;
  float* o = out + (size_t)n*576;
  for (int p=threadIdx.x; p<576; p+=256){
    float v;
    if (p<64){
      float x = d[p];
      v = x/(1.f+expf(-x)) + sc[p];
    } else if (p<256){
      int r = p-64; int f = r/3, c = r-3*f;
      float g = d[64+f]; g = g/(1.f+expf(-g));
      v = d[192+64*c+f]*g + sc[p];
    } else {
      int r = p-256; int f = r/5, c = r-5*f;
      float g = d[128+f]; g = g/(1.f+expf(-g));
      v = d[384+64*c+f]*g + sc[p];
    }
    o[p] = v;
  }
}

// ---------------- host ----------------
extern "C" void kernel_launch(void* const* d_in, const int* in_sizes, int n_in,
                              void* d_out, int out_size, void* d_ws, size_t ws_size,
                              hipStream_t stream)
{
  const float* vectors    =(const float*)d_in[0];
  const float* node_feats =(const float*)d_in[1];
  const int*   node_specie=(const int*)  d_in[2];
  const int*   senders    =(const int*)  d_in[3];
  const int*   receivers  =(const int*)  d_in[4];
  const float* Wsc0=(const float*)d_in[5];
  const float* Wsc1=(const float*)d_in[6];
  const float* Wsc2=(const float*)d_in[7];
  const float* Wu0 =(const float*)d_in[8];
  const float* Wu1 =(const float*)d_in[9];
  const float* Wu2 =(const float*)d_in[10];
  const float* Wm1 =(const float*)d_in[11];
  const float* Wm2 =(const float*)d_in[12];
  const float* Wm3 =(const float*)d_in[13];
  const float* Wd0 =(const float*)d_in[14];
  const float* Wd1 =(const float*)d_in[15];
  const float* Wd2 =(const float*)d_in[16];
  float* out = (float*)d_out;

  int E = in_sizes[0]/3;
  int N = in_sizes[1]/576;
  int nspec = in_sizes[5]/4096;

  // workspace carve
  float* cgbuf     = (float*)d_ws;                         // 512
  float* g_packed  = cgbuf + 512;                          // N*576
  float* sc_packed = g_packed  + (size_t)N*576;            // N*576
  float* a_packed  = sc_packed + (size_t)N*576;            // N*2752
  float* radbuf    = a_packed + (size_t)N*2752;            // E*8
  float* shbuf     = radbuf + (size_t)E*8;                 // E*16
  float* wtabbuf   = shbuf + (size_t)E*16;                 // E*104
  float* h2buf     = wtabbuf + (size_t)E*104;              // E*64
  int*   counts    = (int*)(h2buf + (size_t)E*64);         // N
  int*   offsets   = counts + N;                           // N+1
  int*   cursor    = offsets + (N+1);                      // N
  int*   edge_list = cursor + N;                           // E
  int*   spos      = edge_list + E;                        // E
  size_t used_bytes = (size_t)((char*)(spos + E) - (char*)d_ws);
  used_bytes = (used_bytes + 255) & ~(size_t)255;
  size_t avail = (ws_size > used_bytes) ? (ws_size - used_bytes) : 0;
  long long cap = (long long)(avail / (832u*4u));
  if (cap > E) cap = E;
  cap = (cap/8)*8;
  if (cap < 8) cap = 8;
  float* mixbuf = (float*)((char*)d_ws + used_bytes);      // cap*832
  float* dbuf   = mixbuf;                                  // reuse after rounds: N*704

  hipMemsetAsync(counts, 0, (size_t)N*sizeof(int), stream);
  cg_init_kernel<<<2,256,0,stream>>>(cgbuf);
  if (nspec == 1){
    dim3 grid((N+63)/64, 18);
    node_gemm_kernel<<<grid,256,0,stream>>>(node_feats,Wsc0,Wsc1,Wsc2,Wu0,Wu1,Wu2,
                                            g_packed,sc_packed,N);
  } else {
    node_linear_kernel<<<N,256,0,stream>>>(node_feats,node_specie,Wsc0,Wsc1,Wsc2,Wu0,Wu1,Wu2,
                                           g_packed,sc_packed,N);
  }
  count_kernel<<<(E+255)/256,256,0,stream>>>(receivers,counts,E);
  scan_kernel<<<1,1024,0,stream>>>(counts,offsets,cursor,N);
  scatter_kernel<<<(E+255)/256,256,0,stream>>>(receivers,cursor,edge_list,E);
  geom_kernel<<<(E+255)/256,256,0,stream>>>(vectors,edge_list,senders,radbuf,shbuf,spos,E);
  {
    long long tasks = (long long)E*104;
    wtab_kernel<<<(unsigned)((tasks+255)/256),256,0,stream>>>(shbuf,cgbuf,wtabbuf,E);
  }
  h12_kernel<<<(E+3)/4,256,0,stream>>>(radbuf,Wm1,Wm2,h2buf,E);

  for (long long lo=0; lo<E; lo+=cap){
    long long hi = lo + cap; if (hi > E) hi = E;
    int cnt = (int)(hi - lo);
    {
      dim3 grid((cnt+63)/64, 13);
      mix_gemm_kernel<<<grid,256,0,stream>>>(h2buf,Wm3,mixbuf,(int)lo,cnt);
    }
    node_accum_kernel<<<N,256,0,stream>>>(g_packed,spos,shbuf,wtabbuf,mixbuf,offsets,
                                          a_packed,(int)lo,(int)hi,N);
  }

  {
    dim3 grid((N+31)/32, 11);
    out_gemm_kernel<<<grid,256,0,stream>>>(a_packed,Wd0,Wd1,Wd2,dbuf,N);
  }
  epilogue_kernel<<<N,256,0,stream>>>(dbuf,sc_packed,out,N);
}